// Round 13
// baseline (584.440 us; speedup 1.0000x reference)
//
#include <hip/hip_runtime.h>
#include <cstdint>
#include <cstddef>

typedef _Float16 half8 __attribute__((ext_vector_type(8)));
typedef _Float16 half4 __attribute__((ext_vector_type(4)));
typedef float floatx4 __attribute__((ext_vector_type(4)));

#define BATCH 256
#define NCHK 512
#define NVAR 1024
#define EDGE 3072

// ---- check MLP tiling ----
#define KC    96
#define NT1C  26     // hidden 388 -> 416 -> 26 col-tiles of 16 (26 chunks of 1)
// ---- var MLP tiling ----
#define NT1VP 14     // hidden 196 -> 224 -> 14 col-tiles of 16 (pad tiles exact-zero)

__device__ __forceinline__ float gelu_f(float x) {
  // exact gelu via A&S 7.1.26 erf approx, |err(erf)| < 1.5e-7 (table builder only)
  float ax = fabsf(x) * 0.70710678118654752440f;
  float t  = 1.0f / fmaf(0.3275911f, ax, 1.0f);
  float p  = t * (0.254829592f + t * (-0.284496736f + t * (1.421413741f +
             t * (-1.453152027f + t * 1.061405429f))));
  float e  = __expf(-ax * ax);
  float erfv = fmaf(-p, e, 1.0f);
  float s  = copysignf(erfv, x);
  float hx = 0.5f * x;
  return fmaf(hx, s, hx);
}

// PWL gelu from a VALUE-ONLY table (4.1 KB — LDS diet to fit 8 blocks/CU):
// slope = tab[idx+1]-tab[idx] (ds_read2_b32), |err| ~ 2.4e-5.
// Out of range: h += max(t-tc,0)/64 -> exact h=x for x>8; h~0 for x<-8.
__device__ __forceinline__ float gelu_lut(const float* __restrict__ tabv, float x) {
  float t  = fmaf(x, 64.0f, 512.0f);
  float tc = fminf(fmaxf(t, 0.0f), 1023.0f);
  float tf = __builtin_truncf(tc);
  float fr = tc - tf;
  int idx  = (int)tf;
  float y0 = tabv[idx];
  float y1 = tabv[idx + 1];
  float h  = fmaf(fr, y1 - y0, y0);
  return fmaf(fmaxf(t - tc, 0.0f), 0.015625f, h);
}

#define BUILD_TABV(tabv)                                          \
  for (int k_ = threadIdx.x; k_ < 1026; k_ += 256)                \
    tabv[k_] = gelu_f((k_ - 512) * 0.015625f);

__device__ __forceinline__ half4 lo4(half8 v) {
  return __builtin_shufflevector(v, v, 0, 1, 2, 3);
}
__device__ __forceinline__ half4 hi4(half8 v) {
  return __builtin_shufflevector(v, v, 4, 5, 6, 7);
}

// MERGED weight pack, chunk-contiguous per ht:
// wc (check): chunk ht = 384 half8 entries: [0..191] = w1 frags s*64+l,
//   [192..383] = w2 frags np*64+l.
//   w1: [s*64+l][j] = W1[k=s*32+(l>>4)*8+j][n=ht*16+(l&15)]
//   w2: [np*64+l][j] = W2[k=ht*16+(l>>4)*4+(j&3)][n=(2np+(j>>2))*16+(l&15)]
// wv (var): chunk ht = 256 entries: [0..127] = w1v (2 frags), [128..255] = w2v.
// bwp/bwm = cb1 +/- cW1[96] (fp32 exact for sg=+/-1).
__global__ void pack_kernel(const float* __restrict__ cW1, const float* __restrict__ cb1,
                            const float* __restrict__ cW2, const float* __restrict__ cb2,
                            const float* __restrict__ vW1, const float* __restrict__ vb1,
                            const float* __restrict__ vW2, const float* __restrict__ vb2,
                            _Float16* __restrict__ wc, _Float16* __restrict__ wv,
                            float* __restrict__ bwp, float* __restrict__ bwm,
                            float* __restrict__ b2c, float* __restrict__ b1v,
                            float* __restrict__ b2v)
{
  int id = blockIdx.x * 256 + threadIdx.x;
  const int S0 = NT1C * 384;    // 9984 half8 entries
  const int S1 = NT1VP * 256;   // 3584
  if (id < S0) {
    int ht = id / 384, part = id % 384, l = part & 63;
    int q = l >> 4;
    half8 v;
    if (part < 192) {
      int s = part / 64, n = ht * 16 + (l & 15);
      #pragma unroll
      for (int j = 0; j < 8; ++j) {
        int k = s * 32 + q * 8 + j;
        float x = (n < 388) ? cW1[k * 388 + n] : 0.0f;
        v[j] = (_Float16)x;
      }
    } else {
      int np = (part - 192) / 64, c = l & 15;
      #pragma unroll
      for (int j = 0; j < 8; ++j) {
        int k = ht * 16 + q * 4 + (j & 3);
        int n = (2 * np + (j >> 2)) * 16 + c;
        float x = (k < 388) ? cW2[k * 96 + n] : 0.0f;
        v[j] = (_Float16)x;
      }
    }
    *(half8*)(wc + (size_t)id * 8) = v;
    return;
  }
  id -= S0;
  if (id < S1) {
    int ht = id / 256, part = id % 256, l = part & 63;
    int q = l >> 4;
    half8 v;
    if (part < 128) {
      int s = part / 64, n = ht * 16 + (l & 15);
      #pragma unroll
      for (int j = 0; j < 8; ++j) {
        int k = s * 32 + q * 8 + j;                      // row 48 = prior row
        float x = (k < 49 && n < 196) ? vW1[k * 196 + n] : 0.0f;
        v[j] = (_Float16)x;
      }
    } else {
      int np = (part - 128) / 64, c = l & 15;
      #pragma unroll
      for (int j = 0; j < 8; ++j) {
        int k = ht * 16 + q * 4 + (j & 3);
        int n = (2 * np + (j >> 2)) * 16 + c;
        float x = (k < 196 && n < 49) ? vW2[k * 49 + n] : 0.0f;
        v[j] = (_Float16)x;
      }
    }
    *(half8*)(wv + (size_t)id * 8) = v;
    return;
  }
  id -= S1;
  if (id < 416) {
    float b = (id < 388) ? cb1[id] : 0.0f;
    float wx = (id < 388) ? cW1[96 * 388 + id] : 0.0f;
    bwp[id] = b + wx;
    return;
  }
  id -= 416;
  if (id < 416) {
    float b = (id < 388) ? cb1[id] : 0.0f;
    float wx = (id < 388) ? cW1[96 * 388 + id] : 0.0f;
    bwm[id] = b - wx;
    return;
  }
  id -= 416;
  if (id < 96)  { b2c[id]  = cb2[id]; return; }
  id -= 96;
  if (id < 224) { b1v[id]  = (id < 196) ? vb1[id] : 0.0f; return; }
  id -= 224;
  if (id < 64)  { b2v[id]  = (id < 49) ? vb2[id] : 0.0f; return; }
}

__global__ void init_kernel(const int* __restrict__ perm, const float* __restrict__ prior,
                            _Float16* __restrict__ Mc)
{
  int t = blockIdx.x * 256 + threadIdx.x;   // t < BATCH*EDGE
  int b = t / EDGE, k = t - b * EDGE;
  int e = perm[k];
  _Float16* dst = Mc + ((size_t)b * EDGE + e) * 16;
  half8 z  = {0,0,0,0,0,0,0,0};
  half8 z0 = z;
  z0[0] = (_Float16)prior[k / 3];
  *(half8*)dst = z0;
  *(half8*)(dst + 8) = z;
}

// one ht-step of the check MLP, rg=1, all operands from LDS (1-ht chunk = 6 frags)
#define CSTEPL(HTG)                                                                   \
  {                                                                                   \
    half8 wa0 = wb[0 * 64 + l];                                                       \
    half8 wa1 = wb[1 * 64 + l];                                                       \
    half8 wa2 = wb[2 * 64 + l];                                                       \
    half8 wp0 = wb[3 * 64 + l];                                                       \
    half8 wp1 = wb[4 * 64 + l];                                                       \
    half8 wp2 = wb[5 * 64 + l];                                                       \
    floatx4 a = *(const floatx4*)&bwL[sel + (HTG) * 16 + q * 4];                      \
    a = __builtin_amdgcn_mfma_f32_16x16x32_f16(wa0, mb[0], a, 0, 0, 0);               \
    a = __builtin_amdgcn_mfma_f32_16x16x32_f16(wa1, mb[1], a, 0, 0, 0);               \
    a = __builtin_amdgcn_mfma_f32_16x16x32_f16(wa2, mb[2], a, 0, 0, 0);               \
    half4 h;                                                                          \
    _Pragma("unroll")                                                                 \
    for (int r = 0; r < 4; ++r) h[r] = (_Float16)gelu_lut(tabv, a[r]);                \
    acc2[0] = __builtin_amdgcn_mfma_f32_16x16x16f16(lo4(wp0), h, acc2[0], 0, 0, 0);   \
    acc2[1] = __builtin_amdgcn_mfma_f32_16x16x16f16(hi4(wp0), h, acc2[1], 0, 0, 0);   \
    acc2[2] = __builtin_amdgcn_mfma_f32_16x16x16f16(lo4(wp1), h, acc2[2], 0, 0, 0);   \
    acc2[3] = __builtin_amdgcn_mfma_f32_16x16x16f16(hi4(wp1), h, acc2[3], 0, 0, 0);   \
    acc2[4] = __builtin_amdgcn_mfma_f32_16x16x16f16(lo4(wp2), h, acc2[4], 0, 0, 0);   \
    acc2[5] = __builtin_amdgcn_mfma_f32_16x16x16f16(hi4(wp2), h, acc2[5], 0, 0, 0);   \
  }

// Check-node MLP, 16 rows/wave (rg=1), 64 rows/block. Grid 2048 = 8 blocks/CU;
// LDS 19.7 KB/block -> 8 resident -> 32 waves/CU cap (R10 analysis: wave
// count, not registers, was the occupancy ceiling). 1-ht chunks (6 KB)
// reg-staged (R9-proven protocol: load next chunk to regs during compute,
// ds_write + one barrier per chunk). No global_load_lds (de-risk after
// R11/R12 container failures).
__global__ __launch_bounds__(256, 8) void kernelC(
    const _Float16* __restrict__ Mc, const int* __restrict__ synd,
    _Float16* __restrict__ Yc,
    const _Float16* __restrict__ Wp,
    const float* __restrict__ bwp, const float* __restrict__ bwm,
    const float* __restrict__ b2)
{
  __shared__ __attribute__((aligned(16))) half8 wbuf[2][384];   // 12 KB
  __shared__ __attribute__((aligned(16))) float tabv[1026];     // 4.1 KB
  __shared__ __attribute__((aligned(16))) float bwL[832];       // 3.3 KB

  const int tid = threadIdx.x, w = tid >> 6, l = tid & 63;
  const int q = l >> 4, c = l & 15;
  const int r0 = blockIdx.x * 64 + w * 16;
  const half8* W8 = (const half8*)Wp;

  half8 st0, st1 = {0,0,0,0,0,0,0,0};
  st0 = W8[tid];
  if (tid < 128) st1 = W8[256 + tid];
  wbuf[0][tid] = st0;
  if (tid < 128) wbuf[0][256 + tid] = st1;

  BUILD_TABV(tabv)
  for (int k_ = tid; k_ < 416; k_ += 256) {
    bwL[k_]       = bwp[k_];
    bwL[416 + k_] = bwm[k_];
  }

  // Mc fragment (B-operand: lane holds batch-row n = l&15, k = q*8+j)
  half8 mb[3];
  const _Float16* Arow = Mc + (size_t)(r0 + c) * KC;
  #pragma unroll
  for (int ks = 0; ks < 3; ++ks)
    mb[ks] = *(const half8*)(Arow + ks * 32 + q * 8);
  const float sg = 1.0f - 2.0f * (float)synd[r0 + c];
  const int sel = (sg > 0.0f) ? 0 : 416;

  floatx4 acc2[6];
  #pragma unroll
  for (int nt = 0; nt < 6; ++nt)
    acc2[nt] = (floatx4){0.f, 0.f, 0.f, 0.f};

  __syncthreads();

  int cur = 0;
  #pragma unroll 1
  for (int i = 0; i < NT1C; ++i) {
    if (i < NT1C - 1) {                       // issue next-chunk loads early
      st0 = W8[(size_t)(i + 1) * 384 + tid];
      if (tid < 128) st1 = W8[(size_t)(i + 1) * 384 + 256 + tid];
    }
    const half8* wb = (const half8*)wbuf[cur];
    CSTEPL(i)
    if (i < NT1C - 1) {                       // land next chunk, 1 barrier/chunk
      half8* wbn = (half8*)wbuf[cur ^ 1];
      wbn[tid] = st0;
      if (tid < 128) wbn[256 + tid] = st1;
      __syncthreads();
      cur ^= 1;
    }
  }

  const size_t row = (size_t)(r0 + c);
  #pragma unroll
  for (int nt = 0; nt < 6; ++nt) {
    floatx4 bia = *(const floatx4*)(b2 + nt * 16 + q * 4);
    half4 yy;
    #pragma unroll
    for (int r = 0; r < 4; ++r)
      yy[r] = (_Float16)((acc2[nt][r] + bia[r]) * sg);
    *(half4*)(Yc + row * 96 + nt * 16 + q * 4) = yy;
  }
}

// one ht-step of the var MLP, rg=1 (1-ht chunk = 4 frags)
#define VSTEPL(HTG)                                                                   \
  {                                                                                   \
    half8 wa0 = wb[0 * 64 + l];                                                       \
    half8 wa1 = wb[1 * 64 + l];                                                       \
    half8 wp0 = wb[2 * 64 + l];                                                       \
    half8 wp1 = wb[3 * 64 + l];                                                       \
    floatx4 a = *(const floatx4*)&b1L[(HTG) * 16 + q * 4];                            \
    a = __builtin_amdgcn_mfma_f32_16x16x32_f16(wa0, mb[0], a, 0, 0, 0);               \
    a = __builtin_amdgcn_mfma_f32_16x16x32_f16(wa1, mb[1], a, 0, 0, 0);               \
    half4 h;                                                                          \
    _Pragma("unroll")                                                                 \
    for (int r = 0; r < 4; ++r) h[r] = (_Float16)gelu_lut(tabv, a[r]);                \
    acc2[0] = __builtin_amdgcn_mfma_f32_16x16x16f16(lo4(wp0), h, acc2[0], 0, 0, 0);   \
    acc2[1] = __builtin_amdgcn_mfma_f32_16x16x16f16(hi4(wp0), h, acc2[1], 0, 0, 0);   \
    acc2[2] = __builtin_amdgcn_mfma_f32_16x16x16f16(lo4(wp1), h, acc2[2], 0, 0, 0);   \
    acc2[3] = __builtin_amdgcn_mfma_f32_16x16x16f16(hi4(wp1), h, acc2[3], 0, 0, 0);   \
  }

// Variable-node MLP, 16 vars/wave, 64 vars/block, grid 4096. 1-ht chunks
// (4 KB = exactly one half8 per thread), same reg-staged protocol
// (14 chunks; tiles >= 13 are exact-zero padding).
__global__ __launch_bounds__(256, 8) void kernelV(
    const _Float16* __restrict__ Yc, const int* __restrict__ perm,
    const float* __restrict__ prior,
    _Float16* __restrict__ Mc, float* __restrict__ outp,
    const _Float16* __restrict__ Wp,
    const float* __restrict__ b1, const float* __restrict__ b2)
{
  __shared__ __attribute__((aligned(16))) half8 wbuf[2][256];   // 8 KB
  __shared__ __attribute__((aligned(16))) float tabv[1026];     // 4.1 KB
  __shared__ __attribute__((aligned(16))) float b1L[224];       // 0.9 KB

  const int tid = threadIdx.x, w = tid >> 6, l = tid & 63;
  const int q = l >> 4, c = l & 15;
  const int r0 = blockIdx.x * 64 + w * 16;
  const int b  = r0 >> 10;
  const int v0 = r0 & 1023;
  const size_t yb = (size_t)b * EDGE;
  const half8* W8 = (const half8*)Wp;

  half8 st0 = W8[tid];
  wbuf[0][tid] = st0;

  BUILD_TABV(tabv)
  if (tid < 224) b1L[tid] = b1[tid];

  // Xv^T fragment: lane holds var-row n = l&15, k = q*8+j
  half8 mb[2];
  {
    int v = v0 + c;
    int e0 = perm[3 * v + (q >> 1)];
    mb[0] = *(const half8*)(Yc + (yb + e0) * 16 + (q & 1) * 8);
    half8 m1 = {0,0,0,0,0,0,0,0};
    if (q < 2) {
      int e2 = perm[3 * v + 2];
      m1 = *(const half8*)(Yc + (yb + e2) * 16 + q * 8);
    } else if (q == 2) {
      m1[0] = (_Float16)prior[v];
    }
    mb[1] = m1;
  }

  floatx4 acc2[4];
  #pragma unroll
  for (int nt = 0; nt < 4; ++nt)
    acc2[nt] = (floatx4){0.f, 0.f, 0.f, 0.f};

  __syncthreads();

  int cur = 0;
  #pragma unroll 1
  for (int i = 0; i < NT1VP; ++i) {
    if (i < NT1VP - 1)
      st0 = W8[(size_t)(i + 1) * 256 + tid];
    const half8* wb = (const half8*)wbuf[cur];
    VSTEPL(i)
    if (i < NT1VP - 1) {
      half8* wbn = (half8*)wbuf[cur ^ 1];
      wbn[tid] = st0;
      __syncthreads();
      cur ^= 1;
    }
  }

  const float bllr = b2[48];
  {
    int v = v0 + c;
    #pragma unroll
    for (int nt = 0; nt < 3; ++nt) {
      int pe = perm[3 * v + nt];
      floatx4 bia = *(const floatx4*)(b2 + nt * 16 + q * 4);
      half4 yy;
      #pragma unroll
      for (int r = 0; r < 4; ++r)
        yy[r] = (_Float16)(acc2[nt][r] + bia[r]);
      *(half4*)(Mc + (yb + pe) * 16 + q * 4) = yy;
    }
    if (q == 0)
      outp[r0 + c] = acc2[3][0] + bllr;
  }
}

extern "C" void kernel_launch(void* const* d_in, const int* in_sizes, int n_in,
                              void* d_out, int out_size, void* d_ws, size_t ws_size,
                              hipStream_t stream)
{
  const int*   synd  = (const int*)d_in[0];
  const float* prior = (const float*)d_in[2];
  const int*   perm  = (const int*)d_in[3];
  const float* cW1 = (const float*)d_in[4];
  const float* cb1 = (const float*)d_in[5];
  const float* cW2 = (const float*)d_in[6];
  const float* cb2 = (const float*)d_in[7];
  const float* vW1 = (const float*)d_in[8];
  const float* vb1 = (const float*)d_in[9];
  const float* vW2 = (const float*)d_in[10];
  const float* vb2 = (const float*)d_in[11];
  float* outp = (float*)d_out;
  const int T = out_size / (BATCH * NVAR);

  char* p = (char*)d_ws;
  _Float16* Mc = (_Float16*)p; p += (size_t)BATCH * EDGE * 16 * 2;
  _Float16* Yc = (_Float16*)p; p += (size_t)BATCH * EDGE * 16 * 2;
  _Float16* wc = (_Float16*)p; p += (size_t)NT1C * 384 * 8 * 2;
  _Float16* wv = (_Float16*)p; p += (size_t)NT1VP * 256 * 8 * 2;
  float* bwp  = (float*)p; p += 416 * 4;
  float* bwm  = (float*)p; p += 416 * 4;
  float* b2c  = (float*)p; p += 96 * 4;
  float* b1v  = (float*)p; p += 224 * 4;
  float* b2v  = (float*)p; p += 64 * 4;

  const int packN = NT1C * 384 + NT1VP * 256 +
                    416 + 416 + 96 + 224 + 64;   // 14784
  pack_kernel<<<(packN + 255) / 256, 256, 0, stream>>>(
      cW1, cb1, cW2, cb2, vW1, vb1, vW2, vb2,
      wc, wv, bwp, bwm, b2c, b1v, b2v);
  init_kernel<<<(BATCH * EDGE) / 256, 256, 0, stream>>>(perm, prior, Mc);

  for (int t = 0; t < T; ++t) {
    kernelC<<<(BATCH * NCHK) / 64, 256, 0, stream>>>(
        Mc, synd, Yc, wc, bwp, bwm, b2c);
    kernelV<<<(BATCH * NVAR) / 64, 256, 0, stream>>>(
        Yc, perm, prior, Mc, outp + (size_t)t * BATCH * NVAR, wv, b1v, b2v);
  }
}

// Round 14
// 494.696 us; speedup vs baseline: 1.1814x; 1.1814x over previous
//
#include <hip/hip_runtime.h>
#include <cstdint>
#include <cstddef>

typedef _Float16 half8 __attribute__((ext_vector_type(8)));
typedef _Float16 half4 __attribute__((ext_vector_type(4)));
typedef float floatx4 __attribute__((ext_vector_type(4)));

#define BATCH 256
#define NCHK 512
#define NVAR 1024
#define EDGE 3072

// ---- check MLP tiling ----
#define KC    96
#define NT1C  26     // hidden 388 -> 416 -> 26 col-tiles of 16 (13 chunks of 2)
                     // tile 25 (units 400-415) is PURE PAD: skipped in compute
// ---- var MLP tiling ----
#define NT1VP 14     // hidden 196 -> 224 -> 14 col-tiles of 16 (7 chunks of 2)
                     // tile 13 is PURE PAD: skipped in compute

__device__ __forceinline__ float gelu_f(float x) {
  // exact gelu via A&S 7.1.26 erf approx, |err(erf)| < 1.5e-7 (table builder only)
  float ax = fabsf(x) * 0.70710678118654752440f;
  float t  = 1.0f / fmaf(0.3275911f, ax, 1.0f);
  float p  = t * (0.254829592f + t * (-0.284496736f + t * (1.421413741f +
             t * (-1.453152027f + t * 1.061405429f))));
  float e  = __expf(-ax * ax);
  float erfv = fmaf(-p, e, 1.0f);
  float s  = copysignf(erfv, x);
  float hx = 0.5f * x;
  return fmaf(hx, s, hx);
}

// PWL gelu: 1024 segments over [-8,8], node+slope in LDS (float2, ds_read_b64).
// |err| <= (1/64)^2/8 * 0.8 ~ 2.4e-5. Out of range: h += max(t-tc,0)/64.
__device__ __forceinline__ float gelu_lut(const float2* __restrict__ tab, float x) {
  float t  = fmaf(x, 64.0f, 512.0f);
  float tc = fminf(fmaxf(t, 0.0f), 1023.0f);
  float tf = __builtin_truncf(tc);
  float fr = tc - tf;
  int idx  = (int)tf;
  float2 ns = tab[idx];
  float h  = fmaf(fr, ns.y, ns.x);
  return fmaf(fmaxf(t - tc, 0.0f), 0.015625f, h);
}

__device__ __forceinline__ half4 lo4(half8 v) {
  return __builtin_shufflevector(v, v, 0, 1, 2, 3);
}
__device__ __forceinline__ half4 hi4(half8 v) {
  return __builtin_shufflevector(v, v, 4, 5, 6, 7);
}

// Direct global->LDS DMA, 16B per lane (dest = wave-uniform base + lane*16).
__device__ __forceinline__ void gload_lds16(const void* g, void* lds) {
  __builtin_amdgcn_global_load_lds(
      (const __attribute__((address_space(1))) unsigned int*)g,
      (__attribute__((address_space(3))) unsigned int*)lds, 16, 0, 0);
}

// Weight packs, CHUNK-CONTIGUOUS for block-level LDS staging:
// w1c: frag (ht*3 + s): [(ht*3+s)*64 + l][j] = W1[k=s*32+(l>>4)*8+j][n=ht*16+(l&15)]
// w2c: frag (ht*3 + p) (K16 pairs): [..][j] = W2[k=ht*16+(l>>4)*4+(j&3)][n=(2p+(j>>2))*16+(l&15)]
// w1v/w2v: same with 2 frags per ht, NT1VP=14 tiles (pad tiles exact-zero).
// bwp/bwm = cb1 +/- cW1[96] (fp32 exact for sg=+/-1).
__global__ void pack_kernel(const float* __restrict__ cW1, const float* __restrict__ cb1,
                            const float* __restrict__ cW2, const float* __restrict__ cb2,
                            const float* __restrict__ vW1, const float* __restrict__ vb1,
                            const float* __restrict__ vW2, const float* __restrict__ vb2,
                            _Float16* __restrict__ w1c, _Float16* __restrict__ w2c,
                            _Float16* __restrict__ w1v, _Float16* __restrict__ w2v,
                            float* __restrict__ bwp, float* __restrict__ bwm,
                            float* __restrict__ b2c, float* __restrict__ b1v,
                            float* __restrict__ b2v)
{
  int id = blockIdx.x * 256 + threadIdx.x;
  const int S0 = NT1C * 3 * 64;    // 4992
  const int S1 = NT1C * 3 * 64;    // 4992
  const int S2 = NT1VP * 2 * 64;   // 1792
  const int S3 = NT1VP * 2 * 64;   // 1792
  if (id < S0) {
    int fh = id / 64, l = id % 64;
    int ht = fh / 3, s = fh % 3;
    int q = l >> 4, n = ht * 16 + (l & 15);
    half8 v;
    #pragma unroll
    for (int j = 0; j < 8; ++j) {
      int k = s * 32 + q * 8 + j;
      float x = (n < 388) ? cW1[k * 388 + n] : 0.0f;
      v[j] = (_Float16)x;
    }
    *(half8*)(w1c + (size_t)id * 8) = v;
    return;
  }
  id -= S0;
  if (id < S1) {
    int fh = id / 64, l = id % 64;
    int ht = fh / 3, np = fh % 3;
    int q = l >> 4, c = l & 15;
    half8 v;
    #pragma unroll
    for (int j = 0; j < 8; ++j) {
      int k = ht * 16 + q * 4 + (j & 3);
      int n = (2 * np + (j >> 2)) * 16 + c;
      float x = (k < 388) ? cW2[k * 96 + n] : 0.0f;
      v[j] = (_Float16)x;
    }
    *(half8*)(w2c + (size_t)id * 8) = v;
    return;
  }
  id -= S1;
  if (id < S2) {
    int fh = id / 64, l = id % 64;
    int ht = fh / 2, s = fh % 2;
    int q = l >> 4, n = ht * 16 + (l & 15);
    half8 v;
    #pragma unroll
    for (int j = 0; j < 8; ++j) {
      int k = s * 32 + q * 8 + j;                        // row 48 = prior row
      float x = (k < 49 && n < 196) ? vW1[k * 196 + n] : 0.0f;
      v[j] = (_Float16)x;
    }
    *(half8*)(w1v + (size_t)id * 8) = v;
    return;
  }
  id -= S2;
  if (id < S3) {
    int fh = id / 64, l = id % 64;
    int ht = fh / 2, np = fh % 2;
    int q = l >> 4, c = l & 15;
    half8 v;
    #pragma unroll
    for (int j = 0; j < 8; ++j) {
      int k = ht * 16 + q * 4 + (j & 3);
      int n = (2 * np + (j >> 2)) * 16 + c;
      float x = (k < 196 && n < 49) ? vW2[k * 49 + n] : 0.0f;
      v[j] = (_Float16)x;
    }
    *(half8*)(w2v + (size_t)id * 8) = v;
    return;
  }
  id -= S3;
  if (id < 416) {
    float b = (id < 388) ? cb1[id] : 0.0f;
    float wv = (id < 388) ? cW1[96 * 388 + id] : 0.0f;
    bwp[id] = b + wv;
    return;
  }
  id -= 416;
  if (id < 416) {
    float b = (id < 388) ? cb1[id] : 0.0f;
    float wv = (id < 388) ? cW1[96 * 388 + id] : 0.0f;
    bwm[id] = b - wv;
    return;
  }
  id -= 416;
  if (id < 96)  { b2c[id]  = cb2[id]; return; }
  id -= 96;
  if (id < 224) { b1v[id]  = (id < 196) ? vb1[id] : 0.0f; return; }
  id -= 224;
  if (id < 64)  { b2v[id]  = (id < 49) ? vb2[id] : 0.0f; return; }
}

__global__ void init_kernel(const int* __restrict__ perm, const float* __restrict__ prior,
                            _Float16* __restrict__ Mc)
{
  int t = blockIdx.x * 256 + threadIdx.x;   // t < BATCH*EDGE
  int b = t / EDGE, k = t - b * EDGE;
  int e = perm[k];
  _Float16* dst = Mc + ((size_t)b * EDGE + e) * 16;
  half8 z  = {0,0,0,0,0,0,0,0};
  half8 z0 = z;
  z0[0] = (_Float16)prior[k / 3];
  *(half8*)dst = z0;
  *(half8*)(dst + 8) = z;
}

// one ht-step of the check MLP, rg=2, ALL operands from LDS.
#define CSTEPL(HTG, HTS)                                                                 \
  {                                                                                      \
    half8 wa0 = wb[((HTS) * 3 + 0) * 64 + l];                                            \
    half8 wa1 = wb[((HTS) * 3 + 1) * 64 + l];                                            \
    half8 wa2 = wb[((HTS) * 3 + 2) * 64 + l];                                            \
    half8 wp0 = wb[384 + ((HTS) * 3 + 0) * 64 + l];                                      \
    half8 wp1 = wb[384 + ((HTS) * 3 + 1) * 64 + l];                                      \
    half8 wp2 = wb[384 + ((HTS) * 3 + 2) * 64 + l];                                      \
    floatx4 a0 = *(const floatx4*)&bwL[sel0 + (HTG) * 16 + q * 4];                       \
    floatx4 a1 = *(const floatx4*)&bwL[sel1 + (HTG) * 16 + q * 4];                       \
    a0 = __builtin_amdgcn_mfma_f32_16x16x32_f16(wa0, mb[0][0], a0, 0, 0, 0);             \
    a1 = __builtin_amdgcn_mfma_f32_16x16x32_f16(wa0, mb[1][0], a1, 0, 0, 0);             \
    a0 = __builtin_amdgcn_mfma_f32_16x16x32_f16(wa1, mb[0][1], a0, 0, 0, 0);             \
    a1 = __builtin_amdgcn_mfma_f32_16x16x32_f16(wa1, mb[1][1], a1, 0, 0, 0);             \
    a0 = __builtin_amdgcn_mfma_f32_16x16x32_f16(wa2, mb[0][2], a0, 0, 0, 0);             \
    a1 = __builtin_amdgcn_mfma_f32_16x16x32_f16(wa2, mb[1][2], a1, 0, 0, 0);             \
    half4 h0, h1;                                                                        \
    _Pragma("unroll")                                                                    \
    for (int r = 0; r < 4; ++r) h0[r] = (_Float16)gelu_lut(tab, a0[r]);                  \
    _Pragma("unroll")                                                                    \
    for (int r = 0; r < 4; ++r) h1[r] = (_Float16)gelu_lut(tab, a1[r]);                  \
    acc2[0][0] = __builtin_amdgcn_mfma_f32_16x16x16f16(lo4(wp0), h0, acc2[0][0], 0,0,0); \
    acc2[1][0] = __builtin_amdgcn_mfma_f32_16x16x16f16(lo4(wp0), h1, acc2[1][0], 0,0,0); \
    acc2[0][1] = __builtin_amdgcn_mfma_f32_16x16x16f16(hi4(wp0), h0, acc2[0][1], 0,0,0); \
    acc2[1][1] = __builtin_amdgcn_mfma_f32_16x16x16f16(hi4(wp0), h1, acc2[1][1], 0,0,0); \
    acc2[0][2] = __builtin_amdgcn_mfma_f32_16x16x16f16(lo4(wp1), h0, acc2[0][2], 0,0,0); \
    acc2[1][2] = __builtin_amdgcn_mfma_f32_16x16x16f16(lo4(wp1), h1, acc2[1][2], 0,0,0); \
    acc2[0][3] = __builtin_amdgcn_mfma_f32_16x16x16f16(hi4(wp1), h0, acc2[0][3], 0,0,0); \
    acc2[1][3] = __builtin_amdgcn_mfma_f32_16x16x16f16(hi4(wp1), h1, acc2[1][3], 0,0,0); \
    acc2[0][4] = __builtin_amdgcn_mfma_f32_16x16x16f16(lo4(wp2), h0, acc2[0][4], 0,0,0); \
    acc2[1][4] = __builtin_amdgcn_mfma_f32_16x16x16f16(lo4(wp2), h1, acc2[1][4], 0,0,0); \
    acc2[0][5] = __builtin_amdgcn_mfma_f32_16x16x16f16(hi4(wp2), h0, acc2[0][5], 0,0,0); \
    acc2[1][5] = __builtin_amdgcn_mfma_f32_16x16x16f16(hi4(wp2), h1, acc2[1][5], 0,0,0); \
  }

// wave w DMA-stages its 3 of 12 segments of chunk CH into wbuf[BUF].
// Chunk = 384 entries of w1c (6 segs) + 384 of w2c (6 segs), 6144 B each.
#define CSTAGE(CH, BUF)                                                      \
  {                                                                          \
    if (w < 2) {                                                             \
      const char* gsrc = (const char*)W1p + (size_t)(CH) * 6144;             \
      _Pragma("unroll")                                                      \
      for (int s_ = 0; s_ < 3; ++s_)                                         \
        gload_lds16(gsrc + (((w * 3 + s_) * 64 + l) << 4),                   \
                    &wbuf[BUF][(w * 3 + s_) * 64]);                          \
    } else {                                                                 \
      const char* gsrc = (const char*)W2p + (size_t)(CH) * 6144;             \
      _Pragma("unroll")                                                      \
      for (int s_ = 0; s_ < 3; ++s_)                                         \
        gload_lds16(gsrc + ((((w - 2) * 3 + s_) * 64 + l) << 4),             \
                    &wbuf[BUF][(6 + (w - 2) * 3 + s_) * 64]);                \
    }                                                                        \
  }

// Check-node MLP, 32 rows/wave, 128 rows/block. Weight chunks (2 ht = 12 KB)
// staged via global_load_lds DMA into double-buffered LDS; issued before the
// compute phase that hides their latency. One __syncthreads per chunk.
// Grid 1024 = 4 blocks/CU. Pure-pad tile 25 skipped (bit-identical output).
__global__ __launch_bounds__(256, 4) void kernelC(
    const _Float16* __restrict__ Mc, const int* __restrict__ synd,
    _Float16* __restrict__ Yc,
    const _Float16* __restrict__ W1p, const _Float16* __restrict__ W2p,
    const float* __restrict__ bwp, const float* __restrict__ bwm,
    const float* __restrict__ b2)
{
  __shared__ float2 tab[1024];                               // 8 KB
  __shared__ __attribute__((aligned(16))) float bwL[832];    // 3.3 KB: [bwp | bwm]
  __shared__ half8 wbuf[2][768];                             // 2 x 12 KB chunks

  const int tid = threadIdx.x, w = tid >> 6, l = tid & 63;
  const int q = l >> 4, c = l & 15;
  const int r0 = blockIdx.x * 128 + w * 32;

  CSTAGE(0, 0)                        // DMA chunk 0 under the prologue fills

  // ---- prologue fills (one barrier covers all, incl. DMA vmcnt) ----
  for (int k_ = tid; k_ < 1024; k_ += 256) {
    float x_  = (k_ - 512) * 0.015625f;
    float y0_ = gelu_f(x_);
    float y1_ = gelu_f(x_ + 0.015625f);
    tab[k_] = make_float2(y0_, y1_ - y0_);
  }
  for (int k_ = tid; k_ < 416; k_ += 256) {
    bwL[k_]       = bwp[k_];
    bwL[416 + k_] = bwm[k_];
  }

  // Mc fragments (B-operand: lane holds batch-row n = l&15, k = q*8+j)
  half8 mb[2][3];
  float sg[2];
  #pragma unroll
  for (int rg = 0; rg < 2; ++rg) {
    const _Float16* Arow = Mc + (size_t)(r0 + rg * 16 + c) * KC;
    #pragma unroll
    for (int ks = 0; ks < 3; ++ks)
      mb[rg][ks] = *(const half8*)(Arow + ks * 32 + q * 8);
    sg[rg] = 1.0f - 2.0f * (float)synd[r0 + rg * 16 + c];
  }
  const int sel0 = (sg[0] > 0.0f) ? 0 : 416;
  const int sel1 = (sg[1] > 0.0f) ? 0 : 416;

  floatx4 acc2[2][6];
  #pragma unroll
  for (int rg = 0; rg < 2; ++rg)
    #pragma unroll
    for (int nt = 0; nt < 6; ++nt)
      acc2[rg][nt] = (floatx4){0.f, 0.f, 0.f, 0.f};

  __syncthreads();

  int cur = 0;
  #pragma unroll 1
  for (int i = 0; i < 13; ++i) {
    if (i < 12) CSTAGE(i + 1, cur ^ 1)     // issue next-chunk DMA first
    const half8* wb = (const half8*)wbuf[cur];
    CSTEPL(2 * i, 0)
    if (i < 12) {                          // ht 25 is pure pad: skip compute
      CSTEPL(2 * i + 1, 1)
      __syncthreads();                     // drains DMA + publishes next chunk
      cur ^= 1;
    }
  }

  #pragma unroll
  for (int rg = 0; rg < 2; ++rg) {
    const size_t row = (size_t)(r0 + rg * 16 + c);
    #pragma unroll
    for (int nt = 0; nt < 6; ++nt) {
      floatx4 bia = *(const floatx4*)(b2 + nt * 16 + q * 4);
      half4 yy;
      #pragma unroll
      for (int r = 0; r < 4; ++r)
        yy[r] = (_Float16)((acc2[rg][nt][r] + bia[r]) * sg[rg]);
      *(half4*)(Yc + row * 96 + nt * 16 + q * 4) = yy;
    }
  }
}

// one ht-step of the var MLP, rg=2, operands from LDS
#define VSTEPL(HTG, HTS)                                                                 \
  {                                                                                      \
    half8 wa0 = wb[((HTS) * 2 + 0) * 64 + l];                                            \
    half8 wa1 = wb[((HTS) * 2 + 1) * 64 + l];                                            \
    half8 wp0 = wb[256 + ((HTS) * 2 + 0) * 64 + l];                                      \
    half8 wp1 = wb[256 + ((HTS) * 2 + 1) * 64 + l];                                      \
    floatx4 i0 = *(const floatx4*)&b1L[(HTG) * 16 + q * 4];                              \
    floatx4 a0 = i0, a1 = i0;                                                            \
    a0 = __builtin_amdgcn_mfma_f32_16x16x32_f16(wa0, mb[0][0], a0, 0, 0, 0);             \
    a1 = __builtin_amdgcn_mfma_f32_16x16x32_f16(wa0, mb[1][0], a1, 0, 0, 0);             \
    a0 = __builtin_amdgcn_mfma_f32_16x16x32_f16(wa1, mb[0][1], a0, 0, 0, 0);             \
    a1 = __builtin_amdgcn_mfma_f32_16x16x32_f16(wa1, mb[1][1], a1, 0, 0, 0);             \
    half4 h0, h1;                                                                        \
    _Pragma("unroll")                                                                    \
    for (int r = 0; r < 4; ++r) h0[r] = (_Float16)gelu_lut(tab, a0[r]);                  \
    _Pragma("unroll")                                                                    \
    for (int r = 0; r < 4; ++r) h1[r] = (_Float16)gelu_lut(tab, a1[r]);                  \
    acc2[0][0] = __builtin_amdgcn_mfma_f32_16x16x16f16(lo4(wp0), h0, acc2[0][0], 0,0,0); \
    acc2[1][0] = __builtin_amdgcn_mfma_f32_16x16x16f16(lo4(wp0), h1, acc2[1][0], 0,0,0); \
    acc2[0][1] = __builtin_amdgcn_mfma_f32_16x16x16f16(hi4(wp0), h0, acc2[0][1], 0,0,0); \
    acc2[1][1] = __builtin_amdgcn_mfma_f32_16x16x16f16(hi4(wp0), h1, acc2[1][1], 0,0,0); \
    acc2[0][2] = __builtin_amdgcn_mfma_f32_16x16x16f16(lo4(wp1), h0, acc2[0][2], 0,0,0); \
    acc2[1][2] = __builtin_amdgcn_mfma_f32_16x16x16f16(lo4(wp1), h1, acc2[1][2], 0,0,0); \
    acc2[0][3] = __builtin_amdgcn_mfma_f32_16x16x16f16(hi4(wp1), h0, acc2[0][3], 0,0,0); \
    acc2[1][3] = __builtin_amdgcn_mfma_f32_16x16x16f16(hi4(wp1), h1, acc2[1][3], 0,0,0); \
  }

// wave w DMA-stages its 2 of 8 segments of chunk CH (256 w1v + 256 w2v
// entries, 4096 B each array).
#define VSTAGE(CH, BUF)                                                      \
  {                                                                          \
    if (w < 2) {                                                             \
      const char* gsrc = (const char*)W1p + (size_t)(CH) * 4096;             \
      _Pragma("unroll")                                                      \
      for (int s_ = 0; s_ < 2; ++s_)                                         \
        gload_lds16(gsrc + (((w * 2 + s_) * 64 + l) << 4),                   \
                    &wbuf[BUF][(w * 2 + s_) * 64]);                          \
    } else {                                                                 \
      const char* gsrc = (const char*)W2p + (size_t)(CH) * 4096;             \
      _Pragma("unroll")                                                      \
      for (int s_ = 0; s_ < 2; ++s_)                                         \
        gload_lds16(gsrc + ((((w - 2) * 2 + s_) * 64 + l) << 4),             \
                    &wbuf[BUF][(4 + (w - 2) * 2 + s_) * 64]);                \
    }                                                                        \
  }

// Variable-node MLP, 32 vars/wave, 128 vars/block, DMA chunk staging
// (7 chunks of 2 ht; pure-pad tile 13 skipped — bit-identical output).
__global__ __launch_bounds__(256, 4) void kernelV(
    const _Float16* __restrict__ Yc, const int* __restrict__ perm,
    const float* __restrict__ prior,
    _Float16* __restrict__ Mc, float* __restrict__ outp,
    const _Float16* __restrict__ W1p, const _Float16* __restrict__ W2p,
    const float* __restrict__ b1, const float* __restrict__ b2)
{
  __shared__ float2 tab[1024];                               // 8 KB
  __shared__ __attribute__((aligned(16))) float b1L[224];    // 0.9 KB
  __shared__ half8 wbuf[2][512];                             // 2 x 8 KB chunks

  const int tid = threadIdx.x, w = tid >> 6, l = tid & 63;
  const int q = l >> 4, c = l & 15;
  const int r0 = blockIdx.x * 128 + w * 32;
  const int b  = r0 >> 10;
  const int v0 = r0 & 1023;
  const size_t yb = (size_t)b * EDGE;

  VSTAGE(0, 0)

  for (int k_ = tid; k_ < 1024; k_ += 256) {
    float x_  = (k_ - 512) * 0.015625f;
    float y0_ = gelu_f(x_);
    float y1_ = gelu_f(x_ + 0.015625f);
    tab[k_] = make_float2(y0_, y1_ - y0_);
  }
  if (tid < 224) b1L[tid] = b1[tid];

  // Xv^T fragments: lane holds var-row n = l&15, k = q*8+j
  half8 mb[2][2];
  #pragma unroll
  for (int rg = 0; rg < 2; ++rg) {
    int v = v0 + rg * 16 + c;
    int e0 = perm[3 * v + (q >> 1)];
    mb[rg][0] = *(const half8*)(Yc + (yb + e0) * 16 + (q & 1) * 8);
    half8 m1 = {0,0,0,0,0,0,0,0};
    if (q < 2) {
      int e2 = perm[3 * v + 2];
      m1 = *(const half8*)(Yc + (yb + e2) * 16 + q * 8);
    } else if (q == 2) {
      m1[0] = (_Float16)prior[v];
    }
    mb[rg][1] = m1;
  }

  floatx4 acc2[2][4];
  #pragma unroll
  for (int rg = 0; rg < 2; ++rg)
    #pragma unroll
    for (int nt = 0; nt < 4; ++nt)
      acc2[rg][nt] = (floatx4){0.f, 0.f, 0.f, 0.f};

  __syncthreads();

  int cur = 0;
  #pragma unroll 1
  for (int i = 0; i < 7; ++i) {
    if (i < 6) VSTAGE(i + 1, cur ^ 1)
    const half8* wb = (const half8*)wbuf[cur];
    VSTEPL(2 * i, 0)
    if (i < 6) {                           // ht 13 is pure pad: skip compute
      VSTEPL(2 * i + 1, 1)
      __syncthreads();
      cur ^= 1;
    }
  }

  const float bllr = b2[48];
  #pragma unroll
  for (int rg = 0; rg < 2; ++rg) {
    int v = v0 + rg * 16 + c;
    #pragma unroll
    for (int nt = 0; nt < 3; ++nt) {
      int pe = perm[3 * v + nt];
      floatx4 bia = *(const floatx4*)(b2 + nt * 16 + q * 4);
      half4 yy;
      #pragma unroll
      for (int r = 0; r < 4; ++r)
        yy[r] = (_Float16)(acc2[rg][nt][r] + bia[r]);
      *(half4*)(Mc + (yb + pe) * 16 + q * 4) = yy;
    }
    if (q == 0)
      outp[r0 + rg * 16 + c] = acc2[rg][3][0] + bllr;
  }
}

extern "C" void kernel_launch(void* const* d_in, const int* in_sizes, int n_in,
                              void* d_out, int out_size, void* d_ws, size_t ws_size,
                              hipStream_t stream)
{
  const int*   synd  = (const int*)d_in[0];
  const float* prior = (const float*)d_in[2];
  const int*   perm  = (const int*)d_in[3];
  const float* cW1 = (const float*)d_in[4];
  const float* cb1 = (const float*)d_in[5];
  const float* cW2 = (const float*)d_in[6];
  const float* cb2 = (const float*)d_in[7];
  const float* vW1 = (const float*)d_in[8];
  const float* vb1 = (const float*)d_in[9];
  const float* vW2 = (const float*)d_in[10];
  const float* vb2 = (const float*)d_in[11];
  float* outp = (float*)d_out;
  const int T = out_size / (BATCH * NVAR);

  char* p = (char*)d_ws;
  _Float16* Mc  = (_Float16*)p; p += (size_t)BATCH * EDGE * 16 * 2;
  _Float16* Yc  = (_Float16*)p; p += (size_t)BATCH * EDGE * 16 * 2;
  _Float16* w1c = (_Float16*)p; p += (size_t)NT1C * 3 * 64 * 8 * 2;
  _Float16* w2c = (_Float16*)p; p += (size_t)NT1C * 3 * 64 * 8 * 2;
  _Float16* w1v = (_Float16*)p; p += (size_t)NT1VP * 2 * 64 * 8 * 2;
  _Float16* w2v = (_Float16*)p; p += (size_t)NT1VP * 2 * 64 * 8 * 2;
  float* bwp  = (float*)p; p += 416 * 4;
  float* bwm  = (float*)p; p += 416 * 4;
  float* b2c  = (float*)p; p += 96 * 4;
  float* b1v  = (float*)p; p += 224 * 4;
  float* b2v  = (float*)p; p += 64 * 4;

  const int packN = NT1C * 3 * 64 * 2 + NT1VP * 2 * 64 * 2 +
                    416 + 416 + 96 + 224 + 64;   // 14784
  pack_kernel<<<(packN + 255) / 256, 256, 0, stream>>>(
      cW1, cb1, cW2, cb2, vW1, vb1, vW2, vb2,
      w1c, w2c, w1v, w2v, bwp, bwm, b2c, b1v, b2v);
  init_kernel<<<(BATCH * EDGE) / 256, 256, 0, stream>>>(perm, prior, Mc);

  for (int t = 0; t < T; ++t) {
    kernelC<<<(BATCH * NCHK) / 128, 256, 0, stream>>>(
        Mc, synd, Yc, w1c, w2c, bwp, bwm, b2c);
    kernelV<<<(BATCH * NVAR) / 128, 256, 0, stream>>>(
        Yc, perm, prior, Mc, outp + (size_t)t * BATCH * NVAR, w1v, w2v, b1v, b2v);
  }
}

// Round 15
// 466.492 us; speedup vs baseline: 1.2528x; 1.0605x over previous
//
#include <hip/hip_runtime.h>
#include <cstdint>
#include <cstddef>

typedef _Float16 half8 __attribute__((ext_vector_type(8)));
typedef _Float16 half4 __attribute__((ext_vector_type(4)));
typedef float floatx4 __attribute__((ext_vector_type(4)));

#define BATCH 256
#define NCHK 512
#define NVAR 1024
#define EDGE 3072

// ---- check MLP tiling ----
#define KC    96
#define NT1C  26     // hidden 388 -> 416 -> 26 col-tiles of 16 (13 chunks of 2)
                     // tile 25 is PURE PAD: tail chunk computes only step A
// ---- var MLP tiling ----
#define NT1VP 14     // hidden 196 -> 224 -> 14 col-tiles of 16 (7 chunks of 2)
                     // tile 13 is PURE PAD: tail chunk computes only step A

__device__ __forceinline__ float gelu_f(float x) {
  // exact gelu via A&S 7.1.26 erf approx, |err(erf)| < 1.5e-7 (table builder only)
  float ax = fabsf(x) * 0.70710678118654752440f;
  float t  = 1.0f / fmaf(0.3275911f, ax, 1.0f);
  float p  = t * (0.254829592f + t * (-0.284496736f + t * (1.421413741f +
             t * (-1.453152027f + t * 1.061405429f))));
  float e  = __expf(-ax * ax);
  float erfv = fmaf(-p, e, 1.0f);
  float s  = copysignf(erfv, x);
  float hx = 0.5f * x;
  return fmaf(hx, s, hx);
}

// PWL gelu: 1024 segments over [-8,8], node+slope in LDS (float2, ds_read_b64).
// |err| <= (1/64)^2/8 * 0.8 ~ 2.4e-5. Out of range: h += max(t-tc,0)/64.
__device__ __forceinline__ float gelu_lut(const float2* __restrict__ tab, float x) {
  float t  = fmaf(x, 64.0f, 512.0f);
  float tc = fminf(fmaxf(t, 0.0f), 1023.0f);
  float tf = __builtin_truncf(tc);
  float fr = tc - tf;
  int idx  = (int)tf;
  float2 ns = tab[idx];
  float h  = fmaf(fr, ns.y, ns.x);
  return fmaf(fmaxf(t - tc, 0.0f), 0.015625f, h);
}

// Direct global->LDS DMA, 16B per lane (dest = wave-uniform base + lane*16).
__device__ __forceinline__ void gload_lds16(const void* g, void* lds) {
  __builtin_amdgcn_global_load_lds(
      (const __attribute__((address_space(1))) unsigned int*)g,
      (__attribute__((address_space(3))) unsigned int*)lds, 16, 0, 0);
}

// Weight packs, CHUNK-CONTIGUOUS for block-level LDS staging:
// w1c (per ht, 3 frags, K32 A-op): [(ht*3+s)*64+l][j] = W1[k=s*32+(l>>4)*8+j][n=ht*16+(l&15)]
// w2c (per CHUNK htc, 6 frags, K32 A-op with FUSED virtual-k over the chunk's
//   two ht-steps): [(htc*6+nt)*64+l][j] = W2[kp][out=nt*16+(l&15)],
//   kp = 32*htc + 4*(l>>4) + ((j<4) ? j : 16 + j-4)
//   -> matches hcat = (h_stepA, h_stepB) as the K32 B-operand, so GEMM2 is
//   ONE K32 MFMA per out-tile per chunk (was two K16) — 24->12 MFMAs/chunk.
// w1v/w2v: same scheme (2 W1 frags/ht, 4 fused W2 frags/chunk).
// bwp/bwm = cb1 +/- cW1[96] (fp32 exact for sg=+/-1).
__global__ void pack_kernel(const float* __restrict__ cW1, const float* __restrict__ cb1,
                            const float* __restrict__ cW2, const float* __restrict__ cb2,
                            const float* __restrict__ vW1, const float* __restrict__ vb1,
                            const float* __restrict__ vW2, const float* __restrict__ vb2,
                            _Float16* __restrict__ w1c, _Float16* __restrict__ w2c,
                            _Float16* __restrict__ w1v, _Float16* __restrict__ w2v,
                            float* __restrict__ bwp, float* __restrict__ bwm,
                            float* __restrict__ b2c, float* __restrict__ b1v,
                            float* __restrict__ b2v)
{
  int id = blockIdx.x * 256 + threadIdx.x;
  const int S0 = NT1C * 3 * 64;        // 4992
  const int S1 = (NT1C / 2) * 6 * 64;  // 4992
  const int S2 = NT1VP * 2 * 64;       // 1792
  const int S3 = (NT1VP / 2) * 4 * 64; // 1792
  if (id < S0) {
    int fh = id / 64, l = id % 64;
    int ht = fh / 3, s = fh % 3;
    int q = l >> 4, n = ht * 16 + (l & 15);
    half8 v;
    #pragma unroll
    for (int j = 0; j < 8; ++j) {
      int k = s * 32 + q * 8 + j;
      float x = (n < 388) ? cW1[k * 388 + n] : 0.0f;
      v[j] = (_Float16)x;
    }
    *(half8*)(w1c + (size_t)id * 8) = v;
    return;
  }
  id -= S0;
  if (id < S1) {
    int f = id / 64, l = id % 64;
    int htc = f / 6, nt = f % 6;
    int q = l >> 4, n = nt * 16 + (l & 15);
    int kA = 32 * htc + 4 * q;
    half8 v;
    #pragma unroll
    for (int j = 0; j < 8; ++j) {
      int k = (j < 4) ? (kA + j) : (kA + 16 + (j - 4));
      float x = (k < 388) ? cW2[k * 96 + n] : 0.0f;
      v[j] = (_Float16)x;
    }
    *(half8*)(w2c + (size_t)id * 8) = v;
    return;
  }
  id -= S1;
  if (id < S2) {
    int fh = id / 64, l = id % 64;
    int ht = fh / 2, s = fh % 2;
    int q = l >> 4, n = ht * 16 + (l & 15);
    half8 v;
    #pragma unroll
    for (int j = 0; j < 8; ++j) {
      int k = s * 32 + q * 8 + j;                        // row 48 = prior row
      float x = (k < 49 && n < 196) ? vW1[k * 196 + n] : 0.0f;
      v[j] = (_Float16)x;
    }
    *(half8*)(w1v + (size_t)id * 8) = v;
    return;
  }
  id -= S2;
  if (id < S3) {
    int f = id / 64, l = id % 64;
    int htc = f / 4, nt = f % 4;
    int q = l >> 4, n = nt * 16 + (l & 15);
    int kA = 32 * htc + 4 * q;
    half8 v;
    #pragma unroll
    for (int j = 0; j < 8; ++j) {
      int k = (j < 4) ? (kA + j) : (kA + 16 + (j - 4));
      float x = (k < 196 && n < 49) ? vW2[k * 49 + n] : 0.0f;
      v[j] = (_Float16)x;
    }
    *(half8*)(w2v + (size_t)id * 8) = v;
    return;
  }
  id -= S3;
  if (id < 416) {
    float b = (id < 388) ? cb1[id] : 0.0f;
    float wv = (id < 388) ? cW1[96 * 388 + id] : 0.0f;
    bwp[id] = b + wv;
    return;
  }
  id -= 416;
  if (id < 416) {
    float b = (id < 388) ? cb1[id] : 0.0f;
    float wv = (id < 388) ? cW1[96 * 388 + id] : 0.0f;
    bwm[id] = b - wv;
    return;
  }
  id -= 416;
  if (id < 96)  { b2c[id]  = cb2[id]; return; }
  id -= 96;
  if (id < 224) { b1v[id]  = (id < 196) ? vb1[id] : 0.0f; return; }
  id -= 224;
  if (id < 64)  { b2v[id]  = (id < 49) ? vb2[id] : 0.0f; return; }
}

__global__ void init_kernel(const int* __restrict__ perm, const float* __restrict__ prior,
                            _Float16* __restrict__ Mc)
{
  int t = blockIdx.x * 256 + threadIdx.x;   // t < BATCH*EDGE
  int b = t / EDGE, k = t - b * EDGE;
  int e = perm[k];
  _Float16* dst = Mc + ((size_t)b * EDGE + e) * 16;
  half8 z  = {0,0,0,0,0,0,0,0};
  half8 z0 = z;
  z0[0] = (_Float16)prior[k / 3];
  *(half8*)dst = z0;
  *(half8*)(dst + 8) = z;
}

// GEMM1 for one ht-step (check), rg=2: 6 K32 MFMAs + 8 LUT gelu -> H0,H1
#define CG1(WAOFF, HTG, H0, H1)                                                          \
  {                                                                                      \
    half8 wa0 = wb[((WAOFF) + 0) * 64 + l];                                              \
    half8 wa1 = wb[((WAOFF) + 1) * 64 + l];                                              \
    half8 wa2 = wb[((WAOFF) + 2) * 64 + l];                                              \
    floatx4 a0 = *(const floatx4*)&bwL[sel0 + (HTG) * 16 + q * 4];                       \
    floatx4 a1 = *(const floatx4*)&bwL[sel1 + (HTG) * 16 + q * 4];                       \
    a0 = __builtin_amdgcn_mfma_f32_16x16x32_f16(wa0, mb[0][0], a0, 0, 0, 0);             \
    a1 = __builtin_amdgcn_mfma_f32_16x16x32_f16(wa0, mb[1][0], a1, 0, 0, 0);             \
    a0 = __builtin_amdgcn_mfma_f32_16x16x32_f16(wa1, mb[0][1], a0, 0, 0, 0);             \
    a1 = __builtin_amdgcn_mfma_f32_16x16x32_f16(wa1, mb[1][1], a1, 0, 0, 0);             \
    a0 = __builtin_amdgcn_mfma_f32_16x16x32_f16(wa2, mb[0][2], a0, 0, 0, 0);             \
    a1 = __builtin_amdgcn_mfma_f32_16x16x32_f16(wa2, mb[1][2], a1, 0, 0, 0);             \
    _Pragma("unroll")                                                                    \
    for (int r = 0; r < 4; ++r) H0[r] = (_Float16)gelu_lut(tab, a0[r]);                  \
    _Pragma("unroll")                                                                    \
    for (int r = 0; r < 4; ++r) H1[r] = (_Float16)gelu_lut(tab, a1[r]);                  \
  }

// GEMM2 for one chunk (check): hcat(K32) x 6 out-tiles x 2 rg = 12 K32 MFMAs
#define CG2(H0A, H0B, H1A, H1B)                                                          \
  {                                                                                      \
    half8 hc0 = __builtin_shufflevector(H0A, H0B, 0, 1, 2, 3, 4, 5, 6, 7);               \
    half8 hc1 = __builtin_shufflevector(H1A, H1B, 0, 1, 2, 3, 4, 5, 6, 7);               \
    _Pragma("unroll")                                                                    \
    for (int nt = 0; nt < 6; ++nt) {                                                     \
      half8 wp = wb[384 + nt * 64 + l];                                                  \
      acc2[0][nt] = __builtin_amdgcn_mfma_f32_16x16x32_f16(wp, hc0, acc2[0][nt], 0,0,0); \
      acc2[1][nt] = __builtin_amdgcn_mfma_f32_16x16x32_f16(wp, hc1, acc2[1][nt], 0,0,0); \
    }                                                                                    \
  }

// wave w DMA-stages its 3 of 12 segments of chunk CH into wbuf[BUF].
// Chunk = 384 entries of w1c (6 segs) + 384 of w2c (6 segs), 6144 B each.
#define CSTAGE(CH, BUF)                                                      \
  {                                                                          \
    if (w < 2) {                                                             \
      const char* gsrc = (const char*)W1p + (size_t)(CH) * 6144;             \
      _Pragma("unroll")                                                      \
      for (int s_ = 0; s_ < 3; ++s_)                                         \
        gload_lds16(gsrc + (((w * 3 + s_) * 64 + l) << 4),                   \
                    &wbuf[BUF][(w * 3 + s_) * 64]);                          \
    } else {                                                                 \
      const char* gsrc = (const char*)W2p + (size_t)(CH) * 6144;             \
      _Pragma("unroll")                                                      \
      for (int s_ = 0; s_ < 3; ++s_)                                         \
        gload_lds16(gsrc + ((((w - 2) * 3 + s_) * 64 + l) << 4),             \
                    &wbuf[BUF][(6 + (w - 2) * 3 + s_) * 64]);                \
    }                                                                        \
  }

// Check-node MLP, 32 rows/wave, 128 rows/block. Weight chunks (2 ht = 12 KB)
// staged via global_load_lds DMA into double-buffered LDS. One __syncthreads
// per chunk. Grid 1024 = 4 blocks/CU. GEMM2 fused to K32 per chunk (12 MFMAs
// vs 24 K16). Tail chunk: ht 25 is pure pad -> step B replaced by hB = 0
// (bit-identical: packed W2 rows for k >= 388 are zero).
__global__ __launch_bounds__(256, 4) void kernelC(
    const _Float16* __restrict__ Mc, const int* __restrict__ synd,
    _Float16* __restrict__ Yc,
    const _Float16* __restrict__ W1p, const _Float16* __restrict__ W2p,
    const float* __restrict__ bwp, const float* __restrict__ bwm,
    const float* __restrict__ b2)
{
  __shared__ float2 tab[1024];                               // 8 KB
  __shared__ __attribute__((aligned(16))) float bwL[832];    // 3.3 KB: [bwp | bwm]
  __shared__ half8 wbuf[2][768];                             // 2 x 12 KB chunks

  const int tid = threadIdx.x, w = tid >> 6, l = tid & 63;
  const int q = l >> 4, c = l & 15;
  const int r0 = blockIdx.x * 128 + w * 32;

  CSTAGE(0, 0)                        // DMA chunk 0 under the prologue fills

  // ---- prologue fills (one barrier covers all, incl. DMA vmcnt) ----
  for (int k_ = tid; k_ < 1024; k_ += 256) {
    float x_  = (k_ - 512) * 0.015625f;
    float y0_ = gelu_f(x_);
    float y1_ = gelu_f(x_ + 0.015625f);
    tab[k_] = make_float2(y0_, y1_ - y0_);
  }
  for (int k_ = tid; k_ < 416; k_ += 256) {
    bwL[k_]       = bwp[k_];
    bwL[416 + k_] = bwm[k_];
  }

  // Mc fragments (B-operand: lane holds batch-row n = l&15, k = q*8+j)
  half8 mb[2][3];
  float sg[2];
  #pragma unroll
  for (int rg = 0; rg < 2; ++rg) {
    const _Float16* Arow = Mc + (size_t)(r0 + rg * 16 + c) * KC;
    #pragma unroll
    for (int ks = 0; ks < 3; ++ks)
      mb[rg][ks] = *(const half8*)(Arow + ks * 32 + q * 8);
    sg[rg] = 1.0f - 2.0f * (float)synd[r0 + rg * 16 + c];
  }
  const int sel0 = (sg[0] > 0.0f) ? 0 : 416;
  const int sel1 = (sg[1] > 0.0f) ? 0 : 416;

  floatx4 acc2[2][6];
  #pragma unroll
  for (int rg = 0; rg < 2; ++rg)
    #pragma unroll
    for (int nt = 0; nt < 6; ++nt)
      acc2[rg][nt] = (floatx4){0.f, 0.f, 0.f, 0.f};

  __syncthreads();

  int cur = 0;
  #pragma unroll 1
  for (int i = 0; i < 12; ++i) {
    CSTAGE(i + 1, cur ^ 1)            // issue next-chunk DMA first
    const half8* wb = (const half8*)wbuf[cur];
    half4 h0A, h1A, h0B, h1B;
    CG1(0, 2 * i,     h0A, h1A)
    CG1(3, 2 * i + 1, h0B, h1B)
    CG2(h0A, h0B, h1A, h1B)
    __syncthreads();                  // drains DMA + publishes next chunk
    cur ^= 1;
  }
  {                                   // tail chunk 12: ht 24 real, ht 25 pad
    const half8* wb = (const half8*)wbuf[cur];
    half4 h0A, h1A;
    CG1(0, 24, h0A, h1A)
    half4 z4 = {0, 0, 0, 0};
    CG2(h0A, z4, h1A, z4)
  }

  #pragma unroll
  for (int rg = 0; rg < 2; ++rg) {
    const size_t row = (size_t)(r0 + rg * 16 + c);
    #pragma unroll
    for (int nt = 0; nt < 6; ++nt) {
      floatx4 bia = *(const floatx4*)(b2 + nt * 16 + q * 4);
      half4 yy;
      #pragma unroll
      for (int r = 0; r < 4; ++r)
        yy[r] = (_Float16)((acc2[rg][nt][r] + bia[r]) * sg[rg]);
      *(half4*)(Yc + row * 96 + nt * 16 + q * 4) = yy;
    }
  }
}

// GEMM1 for one ht-step (var), rg=2: 4 K32 MFMAs + 8 LUT gelu -> H0,H1
#define VG1(WAOFF, HTG, H0, H1)                                                          \
  {                                                                                      \
    half8 wa0 = wb[((WAOFF) + 0) * 64 + l];                                              \
    half8 wa1 = wb[((WAOFF) + 1) * 64 + l];                                              \
    floatx4 i0 = *(const floatx4*)&b1L[(HTG) * 16 + q * 4];                              \
    floatx4 a0 = i0, a1 = i0;                                                            \
    a0 = __builtin_amdgcn_mfma_f32_16x16x32_f16(wa0, mb[0][0], a0, 0, 0, 0);             \
    a1 = __builtin_amdgcn_mfma_f32_16x16x32_f16(wa0, mb[1][0], a1, 0, 0, 0);             \
    a0 = __builtin_amdgcn_mfma_f32_16x16x32_f16(wa1, mb[0][1], a0, 0, 0, 0);             \
    a1 = __builtin_amdgcn_mfma_f32_16x16x32_f16(wa1, mb[1][1], a1, 0, 0, 0);             \
    _Pragma("unroll")                                                                    \
    for (int r = 0; r < 4; ++r) H0[r] = (_Float16)gelu_lut(tab, a0[r]);                  \
    _Pragma("unroll")                                                                    \
    for (int r = 0; r < 4; ++r) H1[r] = (_Float16)gelu_lut(tab, a1[r]);                  \
  }

// GEMM2 for one chunk (var): 4 out-tiles x 2 rg = 8 K32 MFMAs
#define VG2(H0A, H0B, H1A, H1B)                                                          \
  {                                                                                      \
    half8 hc0 = __builtin_shufflevector(H0A, H0B, 0, 1, 2, 3, 4, 5, 6, 7);               \
    half8 hc1 = __builtin_shufflevector(H1A, H1B, 0, 1, 2, 3, 4, 5, 6, 7);               \
    _Pragma("unroll")                                                                    \
    for (int nt = 0; nt < 4; ++nt) {                                                     \
      half8 wp = wb[256 + nt * 64 + l];                                                  \
      acc2[0][nt] = __builtin_amdgcn_mfma_f32_16x16x32_f16(wp, hc0, acc2[0][nt], 0,0,0); \
      acc2[1][nt] = __builtin_amdgcn_mfma_f32_16x16x32_f16(wp, hc1, acc2[1][nt], 0,0,0); \
    }                                                                                    \
  }

// wave w DMA-stages its 2 of 8 segments of chunk CH (256 w1v + 256 w2v
// entries, 4096 B each array).
#define VSTAGE(CH, BUF)                                                      \
  {                                                                          \
    if (w < 2) {                                                             \
      const char* gsrc = (const char*)W1p + (size_t)(CH) * 4096;             \
      _Pragma("unroll")                                                      \
      for (int s_ = 0; s_ < 2; ++s_)                                         \
        gload_lds16(gsrc + (((w * 2 + s_) * 64 + l) << 4),                   \
                    &wbuf[BUF][(w * 2 + s_) * 64]);                          \
    } else {                                                                 \
      const char* gsrc = (const char*)W2p + (size_t)(CH) * 4096;             \
      _Pragma("unroll")                                                      \
      for (int s_ = 0; s_ < 2; ++s_)                                         \
        gload_lds16(gsrc + ((((w - 2) * 2 + s_) * 64 + l) << 4),             \
                    &wbuf[BUF][(4 + (w - 2) * 2 + s_) * 64]);                \
    }                                                                        \
  }

// Variable-node MLP, 32 vars/wave, 128 vars/block, DMA chunk staging, fused
// K32 GEMM2 (8 MFMAs/chunk vs 16 K16). Tail chunk: ht 13 pad -> hB = 0.
__global__ __launch_bounds__(256, 4) void kernelV(
    const _Float16* __restrict__ Yc, const int* __restrict__ perm,
    const float* __restrict__ prior,
    _Float16* __restrict__ Mc, float* __restrict__ outp,
    const _Float16* __restrict__ W1p, const _Float16* __restrict__ W2p,
    const float* __restrict__ b1, const float* __restrict__ b2)
{
  __shared__ float2 tab[1024];                               // 8 KB
  __shared__ __attribute__((aligned(16))) float b1L[224];    // 0.9 KB
  __shared__ half8 wbuf[2][512];                             // 2 x 8 KB chunks

  const int tid = threadIdx.x, w = tid >> 6, l = tid & 63;
  const int q = l >> 4, c = l & 15;
  const int r0 = blockIdx.x * 128 + w * 32;
  const int b  = r0 >> 10;
  const int v0 = r0 & 1023;
  const size_t yb = (size_t)b * EDGE;

  VSTAGE(0, 0)

  for (int k_ = tid; k_ < 1024; k_ += 256) {
    float x_  = (k_ - 512) * 0.015625f;
    float y0_ = gelu_f(x_);
    float y1_ = gelu_f(x_ + 0.015625f);
    tab[k_] = make_float2(y0_, y1_ - y0_);
  }
  if (tid < 224) b1L[tid] = b1[tid];

  // Xv^T fragments: lane holds var-row n = l&15, k = q*8+j
  half8 mb[2][2];
  #pragma unroll
  for (int rg = 0; rg < 2; ++rg) {
    int v = v0 + rg * 16 + c;
    int e0 = perm[3 * v + (q >> 1)];
    mb[rg][0] = *(const half8*)(Yc + (yb + e0) * 16 + (q & 1) * 8);
    half8 m1 = {0,0,0,0,0,0,0,0};
    if (q < 2) {
      int e2 = perm[3 * v + 2];
      m1 = *(const half8*)(Yc + (yb + e2) * 16 + q * 8);
    } else if (q == 2) {
      m1[0] = (_Float16)prior[v];
    }
    mb[rg][1] = m1;
  }

  floatx4 acc2[2][4];
  #pragma unroll
  for (int rg = 0; rg < 2; ++rg)
    #pragma unroll
    for (int nt = 0; nt < 4; ++nt)
      acc2[rg][nt] = (floatx4){0.f, 0.f, 0.f, 0.f};

  __syncthreads();

  int cur = 0;
  #pragma unroll 1
  for (int i = 0; i < 6; ++i) {
    VSTAGE(i + 1, cur ^ 1)
    const half8* wb = (const half8*)wbuf[cur];
    half4 h0A, h1A, h0B, h1B;
    VG1(0, 2 * i,     h0A, h1A)
    VG1(2, 2 * i + 1, h0B, h1B)
    VG2(h0A, h0B, h1A, h1B)
    __syncthreads();
    cur ^= 1;
  }
  {                                   // tail chunk 6: ht 12 real, ht 13 pad
    const half8* wb = (const half8*)wbuf[cur];
    half4 h0A, h1A;
    VG1(0, 12, h0A, h1A)
    half4 z4 = {0, 0, 0, 0};
    VG2(h0A, z4, h1A, z4)
  }

  const float bllr = b2[48];
  #pragma unroll
  for (int rg = 0; rg < 2; ++rg) {
    int v = v0 + rg * 16 + c;
    #pragma unroll
    for (int nt = 0; nt < 3; ++nt) {
      int pe = perm[3 * v + nt];
      floatx4 bia = *(const floatx4*)(b2 + nt * 16 + q * 4);
      half4 yy;
      #pragma unroll
      for (int r = 0; r < 4; ++r)
        yy[r] = (_Float16)(acc2[rg][nt][r] + bia[r]);
      *(half4*)(Mc + (yb + pe) * 16 + q * 4) = yy;
    }
    if (q == 0)
      outp[r0 + rg * 16 + c] = acc2[rg][3][0] + bllr;
  }
}

extern "C" void kernel_launch(void* const* d_in, const int* in_sizes, int n_in,
                              void* d_out, int out_size, void* d_ws, size_t ws_size,
                              hipStream_t stream)
{
  const int*   synd  = (const int*)d_in[0];
  const float* prior = (const float*)d_in[2];
  const int*   perm  = (const int*)d_in[3];
  const float* cW1 = (const float*)d_in[4];
  const float* cb1 = (const float*)d_in[5];
  const float* cW2 = (const float*)d_in[6];
  const float* cb2 = (const float*)d_in[7];
  const float* vW1 = (const float*)d_in[8];
  const float* vb1 = (const float*)d_in[9];
  const float* vW2 = (const float*)d_in[10];
  const float* vb2 = (const float*)d_in[11];
  float* outp = (float*)d_out;
  const int T = out_size / (BATCH * NVAR);

  char* p = (char*)d_ws;
  _Float16* Mc  = (_Float16*)p; p += (size_t)BATCH * EDGE * 16 * 2;
  _Float16* Yc  = (_Float16*)p; p += (size_t)BATCH * EDGE * 16 * 2;
  _Float16* w1c = (_Float16*)p; p += (size_t)NT1C * 3 * 64 * 8 * 2;
  _Float16* w2c = (_Float16*)p; p += (size_t)(NT1C / 2) * 6 * 64 * 8 * 2;
  _Float16* w1v = (_Float16*)p; p += (size_t)NT1VP * 2 * 64 * 8 * 2;
  _Float16* w2v = (_Float16*)p; p += (size_t)(NT1VP / 2) * 4 * 64 * 8 * 2;
  float* bwp  = (float*)p; p += 416 * 4;
  float* bwm  = (float*)p; p += 416 * 4;
  float* b2c  = (float*)p; p += 96 * 4;
  float* b1v  = (float*)p; p += 224 * 4;
  float* b2v  = (float*)p; p += 64 * 4;

  const int packN = NT1C * 3 * 64 + (NT1C / 2) * 6 * 64 +
                    NT1VP * 2 * 64 + (NT1VP / 2) * 4 * 64 +
                    416 + 416 + 96 + 224 + 64;   // 14784
  pack_kernel<<<(packN + 255) / 256, 256, 0, stream>>>(
      cW1, cb1, cW2, cb2, vW1, vb1, vW2, vb2,
      w1c, w2c, w1v, w2v, bwp, bwm, b2c, b1v, b2v);
  init_kernel<<<(BATCH * EDGE) / 256, 256, 0, stream>>>(perm, prior, Mc);

  for (int t = 0; t < T; ++t) {
    kernelC<<<(BATCH * NCHK) / 128, 256, 0, stream>>>(
        Mc, synd, Yc, w1c, w2c, bwp, bwm, b2c);
    kernelV<<<(BATCH * NVAR) / 128, 256, 0, stream>>>(
        Yc, perm, prior, Mc, outp + (size_t)t * BATCH * NVAR, w1v, w2v, b1v, b2v);
  }
}

// Round 17
// 462.704 us; speedup vs baseline: 1.2631x; 1.0082x over previous
//
#include <hip/hip_runtime.h>
#include <cstdint>
#include <cstddef>

typedef _Float16 half8 __attribute__((ext_vector_type(8)));
typedef _Float16 half4 __attribute__((ext_vector_type(4)));
typedef float floatx4 __attribute__((ext_vector_type(4)));

#define BATCH 256
#define NCHK 512
#define NVAR 1024
#define EDGE 3072

// ---- check MLP tiling ----
#define KC    96
#define NT1C  26     // hidden 388 -> 416 -> 26 col-tiles of 16 (13 chunks of 2)
                     // tile 25 is PURE PAD: tail chunk computes only step A
// ---- var MLP tiling ----
#define NT1VP 14     // hidden 196 -> 224 -> 14 col-tiles of 16 (7 chunks of 2)
                     // tile 13 is PURE PAD: tail chunk computes only step A

__device__ __forceinline__ float gelu_f(float x) {
  // exact gelu via A&S 7.1.26 erf approx, |err(erf)| < 1.5e-7 (table builder only)
  float ax = fabsf(x) * 0.70710678118654752440f;
  float t  = 1.0f / fmaf(0.3275911f, ax, 1.0f);
  float p  = t * (0.254829592f + t * (-0.284496736f + t * (1.421413741f +
             t * (-1.453152027f + t * 1.061405429f))));
  float e  = __expf(-ax * ax);
  float erfv = fmaf(-p, e, 1.0f);
  float s  = copysignf(erfv, x);
  float hx = 0.5f * x;
  return fmaf(hx, s, hx);
}

// PWL gelu: 1024 segments over [-8,8], node+slope in LDS (float2, ds_read_b64).
// |err| <= (1/64)^2/8 * 0.8 ~ 2.4e-5. Out of range: h += max(t-tc,0)/64.
__device__ __forceinline__ float gelu_lut(const float2* __restrict__ tab, float x) {
  float t  = fmaf(x, 64.0f, 512.0f);
  float tc = fminf(fmaxf(t, 0.0f), 1023.0f);
  float tf = __builtin_truncf(tc);
  float fr = tc - tf;
  int idx  = (int)tf;
  float2 ns = tab[idx];
  float h  = fmaf(fr, ns.y, ns.x);
  return fmaf(fmaxf(t - tc, 0.0f), 0.015625f, h);
}

// Direct global->LDS DMA, 16B per lane (dest = wave-uniform base + lane*16).
__device__ __forceinline__ void gload_lds16(const void* g, void* lds) {
  __builtin_amdgcn_global_load_lds(
      (const __attribute__((address_space(1))) unsigned int*)g,
      (__attribute__((address_space(3))) unsigned int*)lds, 16, 0, 0);
}

// Weight packs, CHUNK-CONTIGUOUS for block-level LDS staging:
// w1c (per ht, 3 frags, K32 A-op): [(ht*3+s)*64+l][j] = W1[k=s*32+(l>>4)*8+j][n=ht*16+(l&15)]
// w2c (per CHUNK htc, 6 frags, K32 A-op with FUSED virtual-k over the chunk's
//   two ht-steps): [(htc*6+nt)*64+l][j] = W2[kp][out=nt*16+(l&15)],
//   kp = 32*htc + 4*(l>>4) + ((j<4) ? j : 16 + j-4)
//   -> matches hcat = (h_stepA, h_stepB) as the K32 B-operand: GEMM2 is ONE
//   K32 MFMA per out-tile per chunk.
// w1v/w2v: same scheme (2 W1 frags/ht, 4 fused W2 frags/chunk).
// bwp/bwm = cb1 +/- cW1[96] (fp32 exact for sg=+/-1).
__global__ void pack_kernel(const float* __restrict__ cW1, const float* __restrict__ cb1,
                            const float* __restrict__ cW2, const float* __restrict__ cb2,
                            const float* __restrict__ vW1, const float* __restrict__ vb1,
                            const float* __restrict__ vW2, const float* __restrict__ vb2,
                            _Float16* __restrict__ w1c, _Float16* __restrict__ w2c,
                            _Float16* __restrict__ w1v, _Float16* __restrict__ w2v,
                            float* __restrict__ bwp, float* __restrict__ bwm,
                            float* __restrict__ b2c, float* __restrict__ b1v,
                            float* __restrict__ b2v)
{
  int id = blockIdx.x * 256 + threadIdx.x;
  const int S0 = NT1C * 3 * 64;        // 4992
  const int S1 = (NT1C / 2) * 6 * 64;  // 4992
  const int S2 = NT1VP * 2 * 64;       // 1792
  const int S3 = (NT1VP / 2) * 4 * 64; // 1792
  if (id < S0) {
    int fh = id / 64, l = id % 64;
    int ht = fh / 3, s = fh % 3;
    int q = l >> 4, n = ht * 16 + (l & 15);
    half8 v;
    #pragma unroll
    for (int j = 0; j < 8; ++j) {
      int k = s * 32 + q * 8 + j;
      float x = (n < 388) ? cW1[k * 388 + n] : 0.0f;
      v[j] = (_Float16)x;
    }
    *(half8*)(w1c + (size_t)id * 8) = v;
    return;
  }
  id -= S0;
  if (id < S1) {
    int f = id / 64, l = id % 64;
    int htc = f / 6, nt = f % 6;
    int q = l >> 4, n = nt * 16 + (l & 15);
    int kA = 32 * htc + 4 * q;
    half8 v;
    #pragma unroll
    for (int j = 0; j < 8; ++j) {
      int k = (j < 4) ? (kA + j) : (kA + 16 + (j - 4));
      float x = (k < 388) ? cW2[k * 96 + n] : 0.0f;
      v[j] = (_Float16)x;
    }
    *(half8*)(w2c + (size_t)id * 8) = v;
    return;
  }
  id -= S1;
  if (id < S2) {
    int fh = id / 64, l = id % 64;
    int ht = fh / 2, s = fh % 2;
    int q = l >> 4, n = ht * 16 + (l & 15);
    half8 v;
    #pragma unroll
    for (int j = 0; j < 8; ++j) {
      int k = s * 32 + q * 8 + j;                        // row 48 = prior row
      float x = (k < 49 && n < 196) ? vW1[k * 196 + n] : 0.0f;
      v[j] = (_Float16)x;
    }
    *(half8*)(w1v + (size_t)id * 8) = v;
    return;
  }
  id -= S2;
  if (id < S3) {
    int f = id / 64, l = id % 64;
    int htc = f / 4, nt = f % 4;
    int q = l >> 4, n = nt * 16 + (l & 15);
    int kA = 32 * htc + 4 * q;
    half8 v;
    #pragma unroll
    for (int j = 0; j < 8; ++j) {
      int k = (j < 4) ? (kA + j) : (kA + 16 + (j - 4));
      float x = (k < 196 && n < 49) ? vW2[k * 49 + n] : 0.0f;
      v[j] = (_Float16)x;
    }
    *(half8*)(w2v + (size_t)id * 8) = v;
    return;
  }
  id -= S3;
  if (id < 416) {
    float b = (id < 388) ? cb1[id] : 0.0f;
    float wv = (id < 388) ? cW1[96 * 388 + id] : 0.0f;
    bwp[id] = b + wv;
    return;
  }
  id -= 416;
  if (id < 416) {
    float b = (id < 388) ? cb1[id] : 0.0f;
    float wv = (id < 388) ? cW1[96 * 388 + id] : 0.0f;
    bwm[id] = b - wv;
    return;
  }
  id -= 416;
  if (id < 96)  { b2c[id]  = cb2[id]; return; }
  id -= 96;
  if (id < 224) { b1v[id]  = (id < 196) ? vb1[id] : 0.0f; return; }
  id -= 224;
  if (id < 64)  { b2v[id]  = (id < 49) ? vb2[id] : 0.0f; return; }
}

__global__ void init_kernel(const int* __restrict__ perm, const float* __restrict__ prior,
                            _Float16* __restrict__ Mc)
{
  int t = blockIdx.x * 256 + threadIdx.x;   // t < BATCH*EDGE
  int b = t / EDGE, k = t - b * EDGE;
  int e = perm[k];
  _Float16* dst = Mc + ((size_t)b * EDGE + e) * 16;
  half8 z  = {0,0,0,0,0,0,0,0};
  half8 z0 = z;
  z0[0] = (_Float16)prior[k / 3];
  *(half8*)dst = z0;
  *(half8*)(dst + 8) = z;
}

// GEMM1 for one ht-step (check), rg=2: 6 K32 MFMAs + 8 LUT gelu -> H0,H1
#define CG1(WAOFF, HTG, H0, H1)                                                          \
  {                                                                                      \
    half8 wa0 = wb[((WAOFF) + 0) * 64 + l];                                              \
    half8 wa1 = wb[((WAOFF) + 1) * 64 + l];                                              \
    half8 wa2 = wb[((WAOFF) + 2) * 64 + l];                                              \
    floatx4 a0 = *(const floatx4*)&bwL[sel0 + (HTG) * 16 + q * 4];                       \
    floatx4 a1 = *(const floatx4*)&bwL[sel1 + (HTG) * 16 + q * 4];                       \
    a0 = __builtin_amdgcn_mfma_f32_16x16x32_f16(wa0, mb[0][0], a0, 0, 0, 0);             \
    a1 = __builtin_amdgcn_mfma_f32_16x16x32_f16(wa0, mb[1][0], a1, 0, 0, 0);             \
    a0 = __builtin_amdgcn_mfma_f32_16x16x32_f16(wa1, mb[0][1], a0, 0, 0, 0);             \
    a1 = __builtin_amdgcn_mfma_f32_16x16x32_f16(wa1, mb[1][1], a1, 0, 0, 0);             \
    a0 = __builtin_amdgcn_mfma_f32_16x16x32_f16(wa2, mb[0][2], a0, 0, 0, 0);             \
    a1 = __builtin_amdgcn_mfma_f32_16x16x32_f16(wa2, mb[1][2], a1, 0, 0, 0);             \
    _Pragma("unroll")                                                                    \
    for (int r = 0; r < 4; ++r) H0[r] = (_Float16)gelu_lut(tab, a0[r]);                  \
    _Pragma("unroll")                                                                    \
    for (int r = 0; r < 4; ++r) H1[r] = (_Float16)gelu_lut(tab, a1[r]);                  \
  }

// GEMM2 for one chunk (check): hcat(K32) x 6 out-tiles x 2 rg = 12 K32 MFMAs
#define CG2(H0A, H0B, H1A, H1B)                                                          \
  {                                                                                      \
    half8 hc0 = __builtin_shufflevector(H0A, H0B, 0, 1, 2, 3, 4, 5, 6, 7);               \
    half8 hc1 = __builtin_shufflevector(H1A, H1B, 0, 1, 2, 3, 4, 5, 6, 7);               \
    _Pragma("unroll")                                                                    \
    for (int nt = 0; nt < 6; ++nt) {                                                     \
      half8 wp = wb[384 + nt * 64 + l];                                                  \
      acc2[0][nt] = __builtin_amdgcn_mfma_f32_16x16x32_f16(wp, hc0, acc2[0][nt], 0,0,0); \
      acc2[1][nt] = __builtin_amdgcn_mfma_f32_16x16x32_f16(wp, hc1, acc2[1][nt], 0,0,0); \
    }                                                                                    \
  }

// wave w DMA-stages its 3 of 12 segments of chunk CH into wbuf[BUF].
// Chunk = 384 entries of w1c (6 segs) + 384 of w2c (6 segs), 6144 B each.
#define CSTAGE(CH, BUF)                                                      \
  {                                                                          \
    if (w < 2) {                                                             \
      const char* gsrc = (const char*)W1p + (size_t)(CH) * 6144;             \
      _Pragma("unroll")                                                      \
      for (int s_ = 0; s_ < 3; ++s_)                                         \
        gload_lds16(gsrc + (((w * 3 + s_) * 64 + l) << 4),                   \
                    &wbuf[BUF][(w * 3 + s_) * 64]);                          \
    } else {                                                                 \
      const char* gsrc = (const char*)W2p + (size_t)(CH) * 6144;             \
      _Pragma("unroll")                                                      \
      for (int s_ = 0; s_ < 3; ++s_)                                         \
        gload_lds16(gsrc + ((((w - 2) * 3 + s_) * 64 + l) << 4),             \
                    &wbuf[BUF][(6 + (w - 2) * 3 + s_) * 64]);                \
    }                                                                        \
  }

// Check-node MLP, 32 rows/wave, 128 rows/block. Weight chunks (2 ht = 12 KB)
// staged via global_load_lds DMA into double-buffered LDS. One __syncthreads
// per chunk. Grid 1024 = 4 blocks/CU. GEMM2 fused to K32. Tail chunk: ht 25
// pad -> hB = 0 (bit-identical). s_setprio(1) wraps each chunk's MFMA cluster
// (T5): 4 blocks/CU sit at different chunk phases, so the CU scheduler can
// prefer MFMA-entering waves over DMA-issuing ones.
__global__ __launch_bounds__(256, 4) void kernelC(
    const _Float16* __restrict__ Mc, const int* __restrict__ synd,
    _Float16* __restrict__ Yc,
    const _Float16* __restrict__ W1p, const _Float16* __restrict__ W2p,
    const float* __restrict__ bwp, const float* __restrict__ bwm,
    const float* __restrict__ b2)
{
  __shared__ float2 tab[1024];                               // 8 KB
  __shared__ __attribute__((aligned(16))) float bwL[832];    // 3.3 KB: [bwp | bwm]
  __shared__ half8 wbuf[2][768];                             // 2 x 12 KB chunks

  const int tid = threadIdx.x, w = tid >> 6, l = tid & 63;
  const int q = l >> 4, c = l & 15;
  const int r0 = blockIdx.x * 128 + w * 32;

  CSTAGE(0, 0)                        // DMA chunk 0 under the prologue fills

  // ---- prologue fills (one barrier covers all, incl. DMA vmcnt) ----
  for (int k_ = tid; k_ < 1024; k_ += 256) {
    float x_  = (k_ - 512) * 0.015625f;
    float y0_ = gelu_f(x_);
    float y1_ = gelu_f(x_ + 0.015625f);
    tab[k_] = make_float2(y0_, y1_ - y0_);
  }
  for (int k_ = tid; k_ < 416; k_ += 256) {
    bwL[k_]       = bwp[k_];
    bwL[416 + k_] = bwm[k_];
  }

  // Mc fragments (B-operand: lane holds batch-row n = l&15, k = q*8+j)
  half8 mb[2][3];
  float sg[2];
  #pragma unroll
  for (int rg = 0; rg < 2; ++rg) {
    const _Float16* Arow = Mc + (size_t)(r0 + rg * 16 + c) * KC;
    #pragma unroll
    for (int ks = 0; ks < 3; ++ks)
      mb[rg][ks] = *(const half8*)(Arow + ks * 32 + q * 8);
    sg[rg] = 1.0f - 2.0f * (float)synd[r0 + rg * 16 + c];
  }
  const int sel0 = (sg[0] > 0.0f) ? 0 : 416;
  const int sel1 = (sg[1] > 0.0f) ? 0 : 416;

  floatx4 acc2[2][6];
  #pragma unroll
  for (int rg = 0; rg < 2; ++rg)
    #pragma unroll
    for (int nt = 0; nt < 6; ++nt)
      acc2[rg][nt] = (floatx4){0.f, 0.f, 0.f, 0.f};

  __syncthreads();

  int cur = 0;
  #pragma unroll 1
  for (int i = 0; i < 12; ++i) {
    CSTAGE(i + 1, cur ^ 1)            // issue next-chunk DMA first
    const half8* wb = (const half8*)wbuf[cur];
    half4 h0A, h1A, h0B, h1B;
    __builtin_amdgcn_s_setprio(1);
    CG1(0, 2 * i,     h0A, h1A)
    CG1(3, 2 * i + 1, h0B, h1B)
    CG2(h0A, h0B, h1A, h1B)
    __builtin_amdgcn_s_setprio(0);
    __syncthreads();                  // drains DMA + publishes next chunk
    cur ^= 1;
  }
  {                                   // tail chunk 12: ht 24 real, ht 25 pad
    const half8* wb = (const half8*)wbuf[cur];
    half4 h0A, h1A;
    __builtin_amdgcn_s_setprio(1);
    CG1(0, 24, h0A, h1A)
    half4 z4 = {0, 0, 0, 0};
    CG2(h0A, z4, h1A, z4)
    __builtin_amdgcn_s_setprio(0);
  }

  #pragma unroll
  for (int rg = 0; rg < 2; ++rg) {
    const size_t row = (size_t)(r0 + rg * 16 + c);
    #pragma unroll
    for (int nt = 0; nt < 6; ++nt) {
      floatx4 bia = *(const floatx4*)(b2 + nt * 16 + q * 4);
      half4 yy;
      #pragma unroll
      for (int r = 0; r < 4; ++r)
        yy[r] = (_Float16)((acc2[rg][nt][r] + bia[r]) * sg[rg]);
      *(half4*)(Yc + row * 96 + nt * 16 + q * 4) = yy;
    }
  }
}

// GEMM1 for one ht-step (var), rg=2: 4 K32 MFMAs + 8 LUT gelu -> H0,H1
#define VG1(WAOFF, HTG, H0, H1)                                                          \
  {                                                                                      \
    half8 wa0 = wb[((WAOFF) + 0) * 64 + l];                                              \
    half8 wa1 = wb[((WAOFF) + 1) * 64 + l];                                              \
    floatx4 i0 = *(const floatx4*)&b1L[(HTG) * 16 + q * 4];                              \
    floatx4 a0 = i0, a1 = i0;                                                            \
    a0 = __builtin_amdgcn_mfma_f32_16x16x32_f16(wa0, mb[0][0], a0, 0, 0, 0);             \
    a1 = __builtin_amdgcn_mfma_f32_16x16x32_f16(wa0, mb[1][0], a1, 0, 0, 0);             \
    a0 = __builtin_amdgcn_mfma_f32_16x16x32_f16(wa1, mb[0][1], a0, 0, 0, 0);             \
    a1 = __builtin_amdgcn_mfma_f32_16x16x32_f16(wa1, mb[1][1], a1, 0, 0, 0);             \
    _Pragma("unroll")                                                                    \
    for (int r = 0; r < 4; ++r) H0[r] = (_Float16)gelu_lut(tab, a0[r]);                  \
    _Pragma("unroll")                                                                    \
    for (int r = 0; r < 4; ++r) H1[r] = (_Float16)gelu_lut(tab, a1[r]);                  \
  }

// GEMM2 for one chunk (var): 4 out-tiles x 2 rg = 8 K32 MFMAs
#define VG2(H0A, H0B, H1A, H1B)                                                          \
  {                                                                                      \
    half8 hc0 = __builtin_shufflevector(H0A, H0B, 0, 1, 2, 3, 4, 5, 6, 7);               \
    half8 hc1 = __builtin_shufflevector(H1A, H1B, 0, 1, 2, 3, 4, 5, 6, 7);               \
    _Pragma("unroll")                                                                    \
    for (int nt = 0; nt < 4; ++nt) {                                                     \
      half8 wp = wb[256 + nt * 64 + l];                                                  \
      acc2[0][nt] = __builtin_amdgcn_mfma_f32_16x16x32_f16(wp, hc0, acc2[0][nt], 0,0,0); \
      acc2[1][nt] = __builtin_amdgcn_mfma_f32_16x16x32_f16(wp, hc1, acc2[1][nt], 0,0,0); \
    }                                                                                    \
  }

// wave w DMA-stages its 2 of 8 segments of chunk CH (256 w1v + 256 w2v
// entries, 4096 B each array).
#define VSTAGE(CH, BUF)                                                      \
  {                                                                          \
    if (w < 2) {                                                             \
      const char* gsrc = (const char*)W1p + (size_t)(CH) * 4096;             \
      _Pragma("unroll")                                                      \
      for (int s_ = 0; s_ < 2; ++s_)                                         \
        gload_lds16(gsrc + (((w * 2 + s_) * 64 + l) << 4),                   \
                    &wbuf[BUF][(w * 2 + s_) * 64]);                          \
    } else {                                                                 \
      const char* gsrc = (const char*)W2p + (size_t)(CH) * 4096;             \
      _Pragma("unroll")                                                      \
      for (int s_ = 0; s_ < 2; ++s_)                                         \
        gload_lds16(gsrc + ((((w - 2) * 2 + s_) * 64 + l) << 4),             \
                    &wbuf[BUF][(4 + (w - 2) * 2 + s_) * 64]);                \
    }                                                                        \
  }

// Variable-node MLP, 32 vars/wave, 128 vars/block, DMA chunk staging, fused
// K32 GEMM2. Tail chunk: ht 13 pad -> hB = 0. setprio around MFMA clusters.
__global__ __launch_bounds__(256, 4) void kernelV(
    const _Float16* __restrict__ Yc, const int* __restrict__ perm,
    const float* __restrict__ prior,
    _Float16* __restrict__ Mc, float* __restrict__ outp,
    const _Float16* __restrict__ W1p, const _Float16* __restrict__ W2p,
    const float* __restrict__ b1, const float* __restrict__ b2)
{
  __shared__ float2 tab[1024];                               // 8 KB
  __shared__ __attribute__((aligned(16))) float b1L[224];    // 0.9 KB
  __shared__ half8 wbuf[2][512];                             // 2 x 8 KB chunks

  const int tid = threadIdx.x, w = tid >> 6, l = tid & 63;
  const int q = l >> 4, c = l & 15;
  const int r0 = blockIdx.x * 128 + w * 32;
  const int b  = r0 >> 10;
  const int v0 = r0 & 1023;
  const size_t yb = (size_t)b * EDGE;

  VSTAGE(0, 0)

  for (int k_ = tid; k_ < 1024; k_ += 256) {
    float x_  = (k_ - 512) * 0.015625f;
    float y0_ = gelu_f(x_);
    float y1_ = gelu_f(x_ + 0.015625f);
    tab[k_] = make_float2(y0_, y1_ - y0_);
  }
  if (tid < 224) b1L[tid] = b1[tid];

  // Xv^T fragments: lane holds var-row n = l&15, k = q*8+j
  half8 mb[2][2];
  #pragma unroll
  for (int rg = 0; rg < 2; ++rg) {
    int v = v0 + rg * 16 + c;
    int e0 = perm[3 * v + (q >> 1)];
    mb[rg][0] = *(const half8*)(Yc + (yb + e0) * 16 + (q & 1) * 8);
    half8 m1 = {0,0,0,0,0,0,0,0};
    if (q < 2) {
      int e2 = perm[3 * v + 2];
      m1 = *(const half8*)(Yc + (yb + e2) * 16 + q * 8);
    } else if (q == 2) {
      m1[0] = (_Float16)prior[v];
    }
    mb[rg][1] = m1;
  }

  floatx4 acc2[2][4];
  #pragma unroll
  for (int rg = 0; rg < 2; ++rg)
    #pragma unroll
    for (int nt = 0; nt < 4; ++nt)
      acc2[rg][nt] = (floatx4){0.f, 0.f, 0.f, 0.f};

  __syncthreads();

  int cur = 0;
  #pragma unroll 1
  for (int i = 0; i < 6; ++i) {
    VSTAGE(i + 1, cur ^ 1)
    const half8* wb = (const half8*)wbuf[cur];
    half4 h0A, h1A, h0B, h1B;
    __builtin_amdgcn_s_setprio(1);
    VG1(0, 2 * i,     h0A, h1A)
    VG1(2, 2 * i + 1, h0B, h1B)
    VG2(h0A, h0B, h1A, h1B)
    __builtin_amdgcn_s_setprio(0);
    __syncthreads();
    cur ^= 1;
  }
  {                                   // tail chunk 6: ht 12 real, ht 13 pad
    const half8* wb = (const half8*)wbuf[cur];
    half4 h0A, h1A;
    __builtin_amdgcn_s_setprio(1);
    VG1(0, 12, h0A, h1A)
    half4 z4 = {0, 0, 0, 0};
    VG2(h0A, z4, h1A, z4)
    __builtin_amdgcn_s_setprio(0);
  }

  const float bllr = b2[48];
  #pragma unroll
  for (int rg = 0; rg < 2; ++rg) {
    int v = v0 + rg * 16 + c;
    #pragma unroll
    for (int nt = 0; nt < 3; ++nt) {
      int pe = perm[3 * v + nt];
      floatx4 bia = *(const floatx4*)(b2 + nt * 16 + q * 4);
      half4 yy;
      #pragma unroll
      for (int r = 0; r < 4; ++r)
        yy[r] = (_Float16)(acc2[rg][nt][r] + bia[r]);
      *(half4*)(Mc + (yb + pe) * 16 + q * 4) = yy;
    }
    if (q == 0)
      outp[r0 + rg * 16 + c] = acc2[rg][3][0] + bllr;
  }
}

extern "C" void kernel_launch(void* const* d_in, const int* in_sizes, int n_in,
                              void* d_out, int out_size, void* d_ws, size_t ws_size,
                              hipStream_t stream)
{
  const int*   synd  = (const int*)d_in[0];
  const float* prior = (const float*)d_in[2];
  const int*   perm  = (const int*)d_in[3];
  const float* cW1 = (const float*)d_in[4];
  const float* cb1 = (const float*)d_in[5];
  const float* cW2 = (const float*)d_in[6];
  const float* cb2 = (const float*)d_in[7];
  const float* vW1 = (const float*)d_in[8];
  const float* vb1 = (const float*)d_in[9];
  const float* vW2 = (const float*)d_in[10];
  const float* vb2 = (const float*)d_in[11];
  float* outp = (float*)d_out;
  const int T = out_size / (BATCH * NVAR);

  char* p = (char*)d_ws;
  _Float16* Mc  = (_Float16*)p; p += (size_t)BATCH * EDGE * 16 * 2;
  _Float16* Yc  = (_Float16*)p; p += (size_t)BATCH * EDGE * 16 * 2;
  _Float16* w1c = (_Float16*)p; p += (size_t)NT1C * 3 * 64 * 8 * 2;
  _Float16* w2c = (_Float16*)p; p += (size_t)(NT1C / 2) * 6 * 64 * 8 * 2;
  _Float16* w1v = (_Float16*)p; p += (size_t)NT1VP * 2 * 64 * 8 * 2;
  _Float16* w2v = (_Float16*)p; p += (size_t)(NT1VP / 2) * 4 * 64 * 8 * 2;
  float* bwp  = (float*)p; p += 416 * 4;
  float* bwm  = (float*)p; p += 416 * 4;
  float* b2c  = (float*)p; p += 96 * 4;
  float* b1v  = (float*)p; p += 224 * 4;
  float* b2v  = (float*)p; p += 64 * 4;

  const int packN = NT1C * 3 * 64 + (NT1C / 2) * 6 * 64 +
                    NT1VP * 2 * 64 + (NT1VP / 2) * 4 * 64 +
                    416 + 416 + 96 + 224 + 64;   // 14784
  pack_kernel<<<(packN + 255) / 256, 256, 0, stream>>>(
      cW1, cb1, cW2, cb2, vW1, vb1, vW2, vb2,
      w1c, w2c, w1v, w2v, bwp, bwm, b2c, b1v, b2v);
  init_kernel<<<(BATCH * EDGE) / 256, 256, 0, stream>>>(perm, prior, Mc);

  for (int t = 0; t < T; ++t) {
    kernelC<<<(BATCH * NCHK) / 128, 256, 0, stream>>>(
        Mc, synd, Yc, w1c, w2c, bwp, bwm, b2c);
    kernelV<<<(BATCH * NVAR) / 128, 256, 0, stream>>>(
        Yc, perm, prior, Mc, outp + (size_t)t * BATCH * NVAR, w1v, w2v, b1v, b2v);
  }
}